// Round 4
// baseline (2985.228 us; speedup 1.0000x reference)
//
#include <hip/hip_runtime.h>
#include <hip/hip_fp16.h>
#include <math.h>

#define ND 64
constexpr int SCAN_BLK = 1024;
constexpr int BKT_SHIFT = 9;          // 512 nodes per bucket
constexpr int BCUR_PAD = 64;          // ints -> 256 B per cursor (L2-channel spread)

__device__ __forceinline__ float sigmoidf_(float x){ return 1.f/(1.f+__expf(-x)); }

// ---------------- CSR build ----------------
__global__ void k_degree(const int* __restrict__ col, int* __restrict__ deg, int E){
  int i = blockIdx.x*blockDim.x + threadIdx.x;
  if (i < E) atomicAdd(&deg[col[i]], 1);
}

__global__ void k_dinv(const int* __restrict__ deg, float* __restrict__ dinv, int N){
  int i = blockIdx.x*blockDim.x + threadIdx.x;
  if (i < N) dinv[i] = rsqrtf((float)(deg[i] + 1));   // +1 = self loop
}

__global__ void k_scan1(const int* __restrict__ cnt, int* __restrict__ partial,
                        int* __restrict__ bsum, int n){
  __shared__ int tmp[SCAN_BLK];
  int i = blockIdx.x*SCAN_BLK + threadIdx.x;
  int v = (i<n) ? cnt[i] : 0;
  tmp[threadIdx.x] = v; __syncthreads();
  for (int off=1; off<SCAN_BLK; off<<=1){
    int t = (threadIdx.x>=off) ? tmp[threadIdx.x-off] : 0;
    __syncthreads();
    tmp[threadIdx.x] += t;
    __syncthreads();
  }
  if (i<n) partial[i] = tmp[threadIdx.x];
  if (threadIdx.x==SCAN_BLK-1) bsum[blockIdx.x] = tmp[threadIdx.x];
}

__global__ void k_scan2(int* bsum, int nb){
  if (threadIdx.x==0 && blockIdx.x==0){
    int acc=0;
    for (int b=0;b<nb;b++){ int v=bsum[b]; bsum[b]=acc; acc+=v; }
  }
}

// standard rowptr: rowptr[0]=0, rowptr[i+1]=incl_scan(deg)[i]  (rowptr[N]=E)
__global__ void k_scan3(const int* __restrict__ partial, const int* __restrict__ bsum,
                        int* __restrict__ rowptr, int n){
  int i = blockIdx.x*SCAN_BLK + threadIdx.x;
  if (i<n){
    rowptr[i+1] = partial[i] + bsum[blockIdx.x];
    if (i==0) rowptr[0] = 0;
  }
}

__global__ void k_bcinit(const int* __restrict__ rowptr, int* __restrict__ bcur,
                         int NBK, int N){
  int b = blockIdx.x*blockDim.x + threadIdx.x;
  if (b < NBK){
    int node = b << BKT_SHIFT;
    bcur[b*BCUR_PAD] = rowptr[node < N ? node : N];
  }
}

// pass 1: stage (src,dst) pairs into coarse dst-buckets (positions within a
// bucket are handed out consecutively -> pair writes mostly fill cache lines)
__global__ void k_stage(const int* __restrict__ row, const int* __restrict__ col,
                        int* __restrict__ bcur, int2* __restrict__ pairs, int E){
  int i = blockIdx.x*blockDim.x + threadIdx.x;
  if (i < E){
    int d = col[i];
    int pos = atomicAdd(&bcur[(d >> BKT_SHIFT)*BCUR_PAD], 1);
    pairs[pos] = make_int2(row[i], d);
  }
}

// pass 2: one block per bucket; LDS cursors; csr writes confined to a ~64KB window
__global__ void k_place(const int2* __restrict__ pairs, const int* __restrict__ rowptr,
                        int* __restrict__ csr, int N){
  __shared__ int lcur[1 << BKT_SHIFT];
  int b = blockIdx.x;
  int base = b << BKT_SHIFT;
  int nend = base + (1 << BKT_SHIFT); if (nend > N) nend = N;
  int cnt = nend - base;
  for (int c = threadIdx.x; c < cnt; c += 256) lcur[c] = rowptr[base + c];
  __syncthreads();
  int s = rowptr[base], e = rowptr[nend];
  for (int i = s + threadIdx.x; i < e; i += 256){
    int2 p = pairs[i];
    int pos = atomicAdd(&lcur[p.y - base], 1);
    csr[pos] = p.x;
  }
}

// ---------------- input MLP: out = relu(x @ W0 + b0) ----------------
__global__ void k_input(const float* __restrict__ x, const float* __restrict__ W0,
                        const float* __restrict__ b0, float* __restrict__ out, int N){
  __shared__ float w0s[15*ND];
  __shared__ float b0s[ND];
  int tid = threadIdx.x;
  for (int i=tid; i<15*ND; i+=256) w0s[i] = W0[i];
  if (tid < ND) b0s[tid] = b0[tid];
  __syncthreads();
  int node = blockIdx.x*4 + (tid>>6);
  int f = tid & 63;
  if (node < N){
    float acc = b0s[f];
    const float* xr = x + (size_t)node*15;
    #pragma unroll
    for (int k=0;k<15;k++) acc += xr[k]*w0s[k*ND+f];
    out[(size_t)node*ND+f] = fmaxf(acc, 0.f);
  }
}

// ---------------- g16 = fp16( dinv * (out @ Wc) ) ----------------
__global__ void k_transform(const float* __restrict__ out, const float* __restrict__ Wc,
                            const float* __restrict__ dinv, __half* __restrict__ g, int N){
  __shared__ float wcs[ND*ND];
  __shared__ float xs[16][ND];
  int tid = threadIdx.x;
  for (int i=tid; i<ND*ND; i+=256) wcs[i] = Wc[i];
  int nb = blockIdx.x*16;
  for (int i=tid; i<16*ND; i+=256){
    int n = i>>6, k = i&63; int node = nb+n;
    xs[n][k] = (node<N) ? out[(size_t)node*ND+k] : 0.f;
  }
  __syncthreads();
  int f = tid&63, nq = tid>>6;
  float acc0=0.f, acc1=0.f, acc2=0.f, acc3=0.f;
  #pragma unroll
  for (int k=0;k<ND;k+=4){
    float4 x0 = *(const float4*)&xs[nq*4+0][k];
    float4 x1 = *(const float4*)&xs[nq*4+1][k];
    float4 x2 = *(const float4*)&xs[nq*4+2][k];
    float4 x3 = *(const float4*)&xs[nq*4+3][k];
    float w0 = wcs[(k+0)*ND+f];
    float w1 = wcs[(k+1)*ND+f];
    float w2 = wcs[(k+2)*ND+f];
    float w3 = wcs[(k+3)*ND+f];
    acc0 += w0*x0.x + w1*x0.y + w2*x0.z + w3*x0.w;
    acc1 += w0*x1.x + w1*x1.y + w2*x1.z + w3*x1.w;
    acc2 += w0*x2.x + w1*x2.y + w2*x2.z + w3*x2.w;
    acc3 += w0*x3.x + w1*x3.y + w2*x3.z + w3*x3.w;
  }
  int n0 = nb + nq*4;
  if (n0+0 < N) g[(size_t)(n0+0)*ND+f] = __float2half_rn(dinv[n0+0]*acc0);
  if (n0+1 < N) g[(size_t)(n0+1)*ND+f] = __float2half_rn(dinv[n0+1]*acc1);
  if (n0+2 < N) g[(size_t)(n0+2)*ND+f] = __float2half_rn(dinv[n0+2]*acc2);
  if (n0+3 < N) g[(size_t)(n0+3)*ND+f] = __float2half_rn(dinv[n0+3]*acc3);
}

// ---------------- out[dst] = relu(dinv[dst]*(sum g[src] + g[dst]) + bc) ----------------
// 64 lanes = 2 src rows per step (lane>>5 picks the src, lane&31 the half2 elem)
__global__ void k_gather(const __half2* __restrict__ g2, const int* __restrict__ rowptr,
                         const int* __restrict__ csr, const float* __restrict__ dinv,
                         const float* __restrict__ bc, float* __restrict__ out, int N){
  int tid = threadIdx.x;
  int node = blockIdx.x*4 + (tid>>6);
  if (node >= N) return;
  int lane = tid & 63;
  int half = lane >> 5;
  int le = lane & 31;
  int s = rowptr[node], e = rowptr[node+1];
  float ax0=0.f,ax1=0.f,ax2=0.f,ax3=0.f,ax4=0.f,ax5=0.f,ax6=0.f,ax7=0.f;
  float ay0=0.f,ay1=0.f,ay2=0.f,ay3=0.f,ay4=0.f,ay5=0.f,ay6=0.f,ay7=0.f;
  int i = s;
  for (; i + 16 <= e; i += 16){
    int s0 = csr[i + 0 + half];
    int s1 = csr[i + 2 + half];
    int s2 = csr[i + 4 + half];
    int s3 = csr[i + 6 + half];
    int s4 = csr[i + 8 + half];
    int s5 = csr[i +10 + half];
    int s6 = csr[i +12 + half];
    int s7 = csr[i +14 + half];
    float2 f0 = __half22float2(g2[(size_t)s0*32 + le]);
    float2 f1 = __half22float2(g2[(size_t)s1*32 + le]);
    float2 f2 = __half22float2(g2[(size_t)s2*32 + le]);
    float2 f3 = __half22float2(g2[(size_t)s3*32 + le]);
    float2 f4 = __half22float2(g2[(size_t)s4*32 + le]);
    float2 f5 = __half22float2(g2[(size_t)s5*32 + le]);
    float2 f6 = __half22float2(g2[(size_t)s6*32 + le]);
    float2 f7 = __half22float2(g2[(size_t)s7*32 + le]);
    ax0 += f0.x; ay0 += f0.y;
    ax1 += f1.x; ay1 += f1.y;
    ax2 += f2.x; ay2 += f2.y;
    ax3 += f3.x; ay3 += f3.y;
    ax4 += f4.x; ay4 += f4.y;
    ax5 += f5.x; ay5 += f5.y;
    ax6 += f6.x; ay6 += f6.y;
    ax7 += f7.x; ay7 += f7.y;
  }
  for (; i + 2 <= e; i += 2){
    int src = csr[i + half];
    float2 f = __half22float2(g2[(size_t)src*32 + le]);
    ax0 += f.x; ay0 += f.y;
  }
  if (half == 0){
    if (i < e){
      float2 f = __half22float2(g2[(size_t)csr[i]*32 + le]);
      ax1 += f.x; ay1 += f.y;
    }
    float2 f = __half22float2(g2[(size_t)node*32 + le]);   // self loop
    ax2 += f.x; ay2 += f.y;
  }
  float sx = ((ax0+ax1)+(ax2+ax3)) + ((ax4+ax5)+(ax6+ax7));
  float sy = ((ay0+ay1)+(ay2+ay3)) + ((ay4+ay5)+(ay6+ay7));
  sx += __shfl_xor(sx, 32, 64);
  sy += __shfl_xor(sy, 32, 64);
  if (half == 0){
    float dn = dinv[node];
    float2 bb = ((const float2*)bc)[le];
    float2 r;
    r.x = fmaxf(dn*sx + bb.x, 0.f);
    r.y = fmaxf(dn*sy + bb.y, 0.f);
    ((float2*)out)[(size_t)node*32 + le] = r;
  }
}

// ---------------- per-graph contiguous ranges (batch is sorted) ----------------
__global__ void k_goff(const int* __restrict__ batch, int* __restrict__ goff, int N, int B){
  int i = blockIdx.x*blockDim.x + threadIdx.x;
  if (i >= N) return;
  int b = batch[i];
  if (i == 0){ for (int g2=0; g2<=b; ++g2) goff[g2]=0; }
  else {
    int bp = batch[i-1];
    for (int g2=bp+1; g2<=b; ++g2) goff[g2]=i;
  }
  if (i == N-1){ for (int g2=b+1; g2<=B; ++g2) goff[g2]=N; }
}

// ---------------- LSTM step (8 graphs per block) ----------------
__global__ void k_lstm(const float* __restrict__ Wih, const float* __restrict__ Whh,
                       const float* __restrict__ bih, const float* __restrict__ bhh,
                       float* __restrict__ qs, float* __restrict__ hl, float* __restrict__ cl){
  __shared__ float qsr[8][128];
  __shared__ float hlr[8][64];
  __shared__ float gat[8][256];
  int tid = threadIdx.x;
  int g0 = blockIdx.x*8;
  for (int i=tid; i<8*128; i+=256){ int gg=i>>7, k=i&127; qsr[gg][k] = qs[(size_t)(g0+gg)*128+k]; }
  for (int i=tid; i<8*64;  i+=256){ int gg=i>>6, k=i&63;  hlr[gg][k] = hl[(size_t)(g0+gg)*64+k]; }
  __syncthreads();
  int j = tid;  // gate index 0..255
  float bb = bih[j] + bhh[j];
  float acc[8];
  #pragma unroll
  for (int gg=0; gg<8; gg++) acc[gg] = bb;
  const float* wr = Wih + (size_t)j*128;
  for (int k=0; k<128; k++){
    float w = wr[k];
    #pragma unroll
    for (int gg=0; gg<8; gg++) acc[gg] += w*qsr[gg][k];
  }
  const float* wr2 = Whh + (size_t)j*64;
  for (int k=0; k<64; k++){
    float w = wr2[k];
    #pragma unroll
    for (int gg=0; gg<8; gg++) acc[gg] += w*hlr[gg][k];
  }
  #pragma unroll
  for (int gg=0; gg<8; gg++) gat[gg][j] = acc[gg];
  __syncthreads();
  #pragma unroll
  for (int it=0; it<2; ++it){
    int idx = it*256 + tid;
    int gg = idx>>6, d = idx&63;
    int graph = g0+gg;
    float ig = sigmoidf_(gat[gg][d]);
    float fg = sigmoidf_(gat[gg][64+d]);
    float gv = tanhf(gat[gg][128+d]);
    float og = sigmoidf_(gat[gg][192+d]);
    float c = fg*cl[(size_t)graph*64+d] + ig*gv;
    float h = og*tanhf(c);
    cl[(size_t)graph*64+d] = c;
    hl[(size_t)graph*64+d] = h;
    qs[(size_t)graph*128+d] = h;   // q part of q_star
  }
}

// ---------------- attention pooling, one online-softmax sweep ----------------
__global__ void k_attn(const float* __restrict__ out, const int* __restrict__ goff,
                       const float* __restrict__ hl, float* __restrict__ qs){
  __shared__ float redm[4], redd[4];
  __shared__ float redr[4][64];
  int g = blockIdx.x;
  int tid = threadIdx.x, lane = tid&63, wv = tid>>6;
  int s = goff[g], e = goff[g+1];
  float q = hl[(size_t)g*64+lane];
  float m = -3.0e38f, denom = 0.f, racc = 0.f;
  for (int n=s+wv; n<e; n+=4){
    float v = out[(size_t)n*64+lane];
    float p = v*q;
    #pragma unroll
    for (int off=32; off>=1; off>>=1) p += __shfl_xor(p, off, 64);
    if (p > m){                      // wave-uniform branch
      float sc = __expf(m - p);      // first time: exp(-huge) -> 0
      denom *= sc; racc *= sc; m = p;
    }
    float w = __expf(p - m);
    denom += w; racc += w*v;
  }
  if (lane==0){ redm[wv] = m; redd[wv] = denom; }
  redr[wv][lane] = racc;
  __syncthreads();
  if (wv==0){
    float m0=redm[0], m1=redm[1], m2=redm[2], m3=redm[3];
    float mm = fmaxf(fmaxf(m0,m1), fmaxf(m2,m3));
    float s0=__expf(m0-mm), s1=__expf(m1-mm), s2=__expf(m2-mm), s3=__expf(m3-mm);
    float dt = redd[0]*s0 + redd[1]*s1 + redd[2]*s2 + redd[3]*s3;
    float rs = redr[0][lane]*s0 + redr[1][lane]*s1 + redr[2][lane]*s2 + redr[3][lane]*s3;
    qs[(size_t)g*128+64+lane] = (dt > 0.f) ? rs/dt : 0.f;
  }
}

// ---------------- final MLP ----------------
__global__ void k_final(const float* __restrict__ qs, const float* __restrict__ W1,
                        const float* __restrict__ b1, const float* __restrict__ W2,
                        const float* __restrict__ b2, float* __restrict__ outy){
  __shared__ float qsr[128];
  __shared__ float yy[64];
  int g = blockIdx.x; int t = threadIdx.x;  // 64 threads
  qsr[t]    = qs[(size_t)g*128 + t];
  qsr[64+t] = qs[(size_t)g*128 + 64 + t];
  __syncthreads();
  float acc = b1[t];
  for (int k=0; k<128; k++) acc += qsr[k]*W1[k*64+t];
  yy[t] = fmaxf(acc, 0.f);
  __syncthreads();
  if (t < 12){
    float a2 = b2[t];
    for (int k=0; k<64; k++) a2 += yy[k]*W2[k*12+t];
    outy[(size_t)g*12 + t] = a2;
  }
}

extern "C" void kernel_launch(void* const* d_in, const int* in_sizes, int n_in,
                              void* d_out, int out_size, void* d_ws, size_t ws_size,
                              hipStream_t stream){
  const float* x    = (const float*)d_in[0];
  const int*   ei   = (const int*)d_in[1];
  const int*   batch= (const int*)d_in[2];
  const float* W0   = (const float*)d_in[3];
  const float* b0   = (const float*)d_in[4];
  const float* Wc   = (const float*)d_in[5];
  const float* bc   = (const float*)d_in[6];
  const float* Wih  = (const float*)d_in[7];
  const float* Whh  = (const float*)d_in[8];
  const float* bih  = (const float*)d_in[9];
  const float* bhh  = (const float*)d_in[10];
  const float* W1   = (const float*)d_in[11];
  const float* b1   = (const float*)d_in[12];
  const float* W2   = (const float*)d_in[13];
  const float* b2   = (const float*)d_in[14];
  float* yout = (float*)d_out;

  const int N = in_sizes[0]/15;
  const int E = in_sizes[1]/2;
  const int B = out_size/12;
  const int NBK = (N + (1<<BKT_SHIFT) - 1) >> BKT_SHIFT;
  const int* row = ei;       // sources
  const int* col = ei + E;   // targets

  char* ws = (char*)d_ws;
  size_t off = 0;
  auto alloc = [&](size_t bytes)->void*{
    void* p = ws + off; off = (off + bytes + 255) & ~(size_t)255; return p;
  };
  int*    deg     = (int*)   alloc((size_t)N*4);
  int*    rowptr  = (int*)   alloc((size_t)(N+1)*4);
  int*    partial = (int*)   alloc((size_t)N*4);
  int*    bsum    = (int*)   alloc(4096);
  int*    bcur    = (int*)   alloc((size_t)NBK*BCUR_PAD*4);
  int2*   pairs   = (int2*)  alloc((size_t)E*8);
  int*    csr     = (int*)   alloc((size_t)E*4);
  float*  dinv    = (float*) alloc((size_t)N*4);
  float*  nodef   = (float*) alloc((size_t)N*ND*4);
  __half* gbuf    = (__half*)alloc((size_t)N*ND*2);
  int*    goff    = (int*)   alloc((size_t)(B+1)*4);
  float*  hl      = (float*) alloc((size_t)B*64*4);
  float*  cl      = (float*) alloc((size_t)B*64*4);
  float*  qs      = (float*) alloc((size_t)B*128*4);
  (void)ws_size; (void)n_in;

  hipMemsetAsync(deg,  0, (size_t)N*4, stream);
  hipMemsetAsync(hl,   0, (size_t)B*64*4, stream);
  hipMemsetAsync(cl,   0, (size_t)B*64*4, stream);
  hipMemsetAsync(qs,   0, (size_t)B*128*4, stream);

  k_degree<<<(E+255)/256, 256, 0, stream>>>(col, deg, E);
  k_dinv  <<<(N+255)/256, 256, 0, stream>>>(deg, dinv, N);
  int nb = (N + SCAN_BLK - 1)/SCAN_BLK;
  k_scan1<<<nb, SCAN_BLK, 0, stream>>>(deg, partial, bsum, N);
  k_scan2<<<1, 64, 0, stream>>>(bsum, nb);
  k_scan3<<<nb, SCAN_BLK, 0, stream>>>(partial, bsum, rowptr, N);
  k_bcinit<<<(NBK+255)/256, 256, 0, stream>>>(rowptr, bcur, NBK, N);
  k_stage <<<(E+255)/256, 256, 0, stream>>>(row, col, bcur, pairs, E);
  k_place <<<NBK, 256, 0, stream>>>(pairs, rowptr, csr, N);

  k_input<<<(N+3)/4, 256, 0, stream>>>(x, W0, b0, nodef, N);
  for (int s6=0; s6<6; ++s6){
    k_transform<<<(N+15)/16, 256, 0, stream>>>(nodef, Wc, dinv, gbuf, N);
    k_gather   <<<(N+3)/4,   256, 0, stream>>>((const __half2*)gbuf, rowptr, csr, dinv, bc, nodef, N);
  }

  k_goff<<<(N+255)/256, 256, 0, stream>>>(batch, goff, N, B);
  for (int s6=0; s6<6; ++s6){
    k_lstm<<<B/8, 256, 0, stream>>>(Wih, Whh, bih, bhh, qs, hl, cl);
    k_attn<<<B,   256, 0, stream>>>(nodef, goff, hl, qs);
  }
  k_final<<<B, 64, 0, stream>>>(qs, W1, b1, W2, b2, yout);
}

// Round 5
// 1359.901 us; speedup vs baseline: 2.1952x; 2.1952x over previous
//
#include <hip/hip_runtime.h>
#include <hip/hip_fp16.h>
#include <math.h>

#define ND 64
constexpr int SCAN_BLK = 1024;
constexpr int BKT_SHIFT = 7;          // 128 nodes per bucket (782 buckets)
constexpr int BKT_MASK = (1 << BKT_SHIFT) - 1;
constexpr int BCUR_PAD = 64;          // ints -> 256 B per cursor (L2-channel spread)

__device__ __forceinline__ float sigmoidf_(float x){ return 1.f/(1.f+__expf(-x)); }

// ---------------- CSR build ----------------
__global__ void k_degree(const int* __restrict__ col, int* __restrict__ deg, int E){
  int i = blockIdx.x*blockDim.x + threadIdx.x;
  if (i < E) atomicAdd(&deg[col[i]], 1);
}

__global__ void k_dinv(const int* __restrict__ deg, float* __restrict__ dinv, int N){
  int i = blockIdx.x*blockDim.x + threadIdx.x;
  if (i < N) dinv[i] = rsqrtf((float)(deg[i] + 1));   // +1 = self loop
}

__global__ void k_scan1(const int* __restrict__ cnt, int* __restrict__ partial,
                        int* __restrict__ bsum, int n){
  __shared__ int tmp[SCAN_BLK];
  int i = blockIdx.x*SCAN_BLK + threadIdx.x;
  int v = (i<n) ? cnt[i] : 0;
  tmp[threadIdx.x] = v; __syncthreads();
  for (int off=1; off<SCAN_BLK; off<<=1){
    int t = (threadIdx.x>=off) ? tmp[threadIdx.x-off] : 0;
    __syncthreads();
    tmp[threadIdx.x] += t;
    __syncthreads();
  }
  if (i<n) partial[i] = tmp[threadIdx.x];
  if (threadIdx.x==SCAN_BLK-1) bsum[blockIdx.x] = tmp[threadIdx.x];
}

__global__ void k_scan2(int* bsum, int nb){
  if (threadIdx.x==0 && blockIdx.x==0){
    int acc=0;
    for (int b=0;b<nb;b++){ int v=bsum[b]; bsum[b]=acc; acc+=v; }
  }
}

// standard rowptr: rowptr[0]=0, rowptr[i+1]=incl_scan(deg)[i]  (rowptr[N]=E)
__global__ void k_scan3(const int* __restrict__ partial, const int* __restrict__ bsum,
                        int* __restrict__ rowptr, int n){
  int i = blockIdx.x*SCAN_BLK + threadIdx.x;
  if (i<n){
    rowptr[i+1] = partial[i] + bsum[blockIdx.x];
    if (i==0) rowptr[0] = 0;
  }
}

__global__ void k_bcinit(const int* __restrict__ rowptr, int* __restrict__ bcur,
                         int NBK, int N){
  int b = blockIdx.x*blockDim.x + threadIdx.x;
  if (b < NBK){
    int node = b << BKT_SHIFT;
    bcur[b*BCUR_PAD] = rowptr[node < N ? node : N];
  }
}

// pass 1: stage packed (src<<7 | dst&127) into coarse dst-buckets (positions
// within a bucket are handed out consecutively -> writes mostly fill lines)
__global__ void k_stage(const int* __restrict__ row, const int* __restrict__ col,
                        int* __restrict__ bcur, unsigned* __restrict__ pairs, int E){
  int i = blockIdx.x*blockDim.x + threadIdx.x;
  if (i < E){
    int d = col[i];
    int pos = atomicAdd(&bcur[(d >> BKT_SHIFT)*BCUR_PAD], 1);
    pairs[pos] = ((unsigned)row[i] << BKT_SHIFT) | (unsigned)(d & BKT_MASK);
  }
}

// pass 2: one block per bucket; LDS cursors; csr writes confined to a ~16KB window
__global__ void k_place(const unsigned* __restrict__ pairs, const int* __restrict__ rowptr,
                        int* __restrict__ csr, int N){
  __shared__ int lcur[1 << BKT_SHIFT];
  int b = blockIdx.x;
  int base = b << BKT_SHIFT;
  int nend = base + (1 << BKT_SHIFT); if (nend > N) nend = N;
  int cnt = nend - base;
  for (int c = threadIdx.x; c < cnt; c += 256) lcur[c] = rowptr[base + c];
  __syncthreads();
  int s = rowptr[base], e = rowptr[nend];
  for (int i = s + threadIdx.x; i < e; i += 256){
    unsigned p = pairs[i];
    int pos = atomicAdd(&lcur[p & BKT_MASK], 1);
    csr[pos] = (int)(p >> BKT_SHIFT);
  }
}

// ---------------- input MLP: out = relu(x @ W0 + b0) ----------------
__global__ void k_input(const float* __restrict__ x, const float* __restrict__ W0,
                        const float* __restrict__ b0, float* __restrict__ out, int N){
  __shared__ float w0s[15*ND];
  __shared__ float b0s[ND];
  int tid = threadIdx.x;
  for (int i=tid; i<15*ND; i+=256) w0s[i] = W0[i];
  if (tid < ND) b0s[tid] = b0[tid];
  __syncthreads();
  int node = blockIdx.x*4 + (tid>>6);
  int f = tid & 63;
  if (node < N){
    float acc = b0s[f];
    const float* xr = x + (size_t)node*15;
    #pragma unroll
    for (int k=0;k<15;k++) acc += xr[k]*w0s[k*ND+f];
    out[(size_t)node*ND+f] = fmaxf(acc, 0.f);
  }
}

// ---------------- g16 = fp16( dinv * (out @ Wc) ) ----------------
// (round-2 inner loop — the float4 variant regressed 4x, reverted)
__global__ void k_transform(const float* __restrict__ out, const float* __restrict__ Wc,
                            const float* __restrict__ dinv, __half* __restrict__ g, int N){
  __shared__ float wcs[ND*ND];
  __shared__ float xs[16][ND];
  int tid = threadIdx.x;
  for (int i=tid; i<ND*ND; i+=256) wcs[i] = Wc[i];
  int nb = blockIdx.x*16;
  for (int i=tid; i<16*ND; i+=256){
    int n = i>>6, k = i&63; int node = nb+n;
    xs[n][k] = (node<N) ? out[(size_t)node*ND+k] : 0.f;
  }
  __syncthreads();
  int f = tid&63, nq = tid>>6;
  float acc0=0.f, acc1=0.f, acc2=0.f, acc3=0.f;
  #pragma unroll 16
  for (int k=0;k<ND;k++){
    float w = wcs[k*ND+f];
    acc0 += w*xs[nq*4+0][k];
    acc1 += w*xs[nq*4+1][k];
    acc2 += w*xs[nq*4+2][k];
    acc3 += w*xs[nq*4+3][k];
  }
  int n0 = nb + nq*4;
  if (n0+0 < N) g[(size_t)(n0+0)*ND+f] = __float2half_rn(dinv[n0+0]*acc0);
  if (n0+1 < N) g[(size_t)(n0+1)*ND+f] = __float2half_rn(dinv[n0+1]*acc1);
  if (n0+2 < N) g[(size_t)(n0+2)*ND+f] = __float2half_rn(dinv[n0+2]*acc2);
  if (n0+3 < N) g[(size_t)(n0+3)*ND+f] = __float2half_rn(dinv[n0+3]*acc3);
}

// ---------------- out[dst] = relu(dinv[dst]*(sum g[src] + g[dst]) + bc) ----------------
// 64 lanes = 2 src rows per step (lane>>5 picks the src, lane&31 the half2 elem)
__global__ void k_gather(const __half2* __restrict__ g2, const int* __restrict__ rowptr,
                         const int* __restrict__ csr, const float* __restrict__ dinv,
                         const float* __restrict__ bc, float* __restrict__ out, int N){
  int tid = threadIdx.x;
  int node = blockIdx.x*4 + (tid>>6);
  if (node >= N) return;
  int lane = tid & 63;
  int half = lane >> 5;
  int le = lane & 31;
  int s = rowptr[node], e = rowptr[node+1];
  float ax0=0.f,ax1=0.f,ax2=0.f,ax3=0.f,ax4=0.f,ax5=0.f,ax6=0.f,ax7=0.f;
  float ay0=0.f,ay1=0.f,ay2=0.f,ay3=0.f,ay4=0.f,ay5=0.f,ay6=0.f,ay7=0.f;
  int i = s;
  for (; i + 16 <= e; i += 16){
    int s0 = csr[i + 0 + half];
    int s1 = csr[i + 2 + half];
    int s2 = csr[i + 4 + half];
    int s3 = csr[i + 6 + half];
    int s4 = csr[i + 8 + half];
    int s5 = csr[i +10 + half];
    int s6 = csr[i +12 + half];
    int s7 = csr[i +14 + half];
    float2 f0 = __half22float2(g2[(size_t)s0*32 + le]);
    float2 f1 = __half22float2(g2[(size_t)s1*32 + le]);
    float2 f2 = __half22float2(g2[(size_t)s2*32 + le]);
    float2 f3 = __half22float2(g2[(size_t)s3*32 + le]);
    float2 f4 = __half22float2(g2[(size_t)s4*32 + le]);
    float2 f5 = __half22float2(g2[(size_t)s5*32 + le]);
    float2 f6 = __half22float2(g2[(size_t)s6*32 + le]);
    float2 f7 = __half22float2(g2[(size_t)s7*32 + le]);
    ax0 += f0.x; ay0 += f0.y;
    ax1 += f1.x; ay1 += f1.y;
    ax2 += f2.x; ay2 += f2.y;
    ax3 += f3.x; ay3 += f3.y;
    ax4 += f4.x; ay4 += f4.y;
    ax5 += f5.x; ay5 += f5.y;
    ax6 += f6.x; ay6 += f6.y;
    ax7 += f7.x; ay7 += f7.y;
  }
  for (; i + 2 <= e; i += 2){
    int src = csr[i + half];
    float2 f = __half22float2(g2[(size_t)src*32 + le]);
    ax0 += f.x; ay0 += f.y;
  }
  if (half == 0){
    if (i < e){
      float2 f = __half22float2(g2[(size_t)csr[i]*32 + le]);
      ax1 += f.x; ay1 += f.y;
    }
    float2 f = __half22float2(g2[(size_t)node*32 + le]);   // self loop
    ax2 += f.x; ay2 += f.y;
  }
  float sx = ((ax0+ax1)+(ax2+ax3)) + ((ax4+ax5)+(ax6+ax7));
  float sy = ((ay0+ay1)+(ay2+ay3)) + ((ay4+ay5)+(ay6+ay7));
  sx += __shfl_xor(sx, 32, 64);
  sy += __shfl_xor(sy, 32, 64);
  if (half == 0){
    float dn = dinv[node];
    float2 bb = ((const float2*)bc)[le];
    float2 r;
    r.x = fmaxf(dn*sx + bb.x, 0.f);
    r.y = fmaxf(dn*sy + bb.y, 0.f);
    ((float2*)out)[(size_t)node*32 + le] = r;
  }
}

// ---------------- per-graph contiguous ranges (batch is sorted) ----------------
__global__ void k_goff(const int* __restrict__ batch, int* __restrict__ goff, int N, int B){
  int i = blockIdx.x*blockDim.x + threadIdx.x;
  if (i >= N) return;
  int b = batch[i];
  if (i == 0){ for (int g2=0; g2<=b; ++g2) goff[g2]=0; }
  else {
    int bp = batch[i-1];
    for (int g2=bp+1; g2<=b; ++g2) goff[g2]=i;
  }
  if (i == N-1){ for (int g2=b+1; g2<=B; ++g2) goff[g2]=N; }
}

// ---------------- LSTM step (8 graphs per block) ----------------
__global__ void k_lstm(const float* __restrict__ Wih, const float* __restrict__ Whh,
                       const float* __restrict__ bih, const float* __restrict__ bhh,
                       float* __restrict__ qs, float* __restrict__ hl, float* __restrict__ cl){
  __shared__ float qsr[8][128];
  __shared__ float hlr[8][64];
  __shared__ float gat[8][256];
  int tid = threadIdx.x;
  int g0 = blockIdx.x*8;
  for (int i=tid; i<8*128; i+=256){ int gg=i>>7, k=i&127; qsr[gg][k] = qs[(size_t)(g0+gg)*128+k]; }
  for (int i=tid; i<8*64;  i+=256){ int gg=i>>6, k=i&63;  hlr[gg][k] = hl[(size_t)(g0+gg)*64+k]; }
  __syncthreads();
  int j = tid;  // gate index 0..255
  float bb = bih[j] + bhh[j];
  float acc[8];
  #pragma unroll
  for (int gg=0; gg<8; gg++) acc[gg] = bb;
  const float* wr = Wih + (size_t)j*128;
  for (int k=0; k<128; k++){
    float w = wr[k];
    #pragma unroll
    for (int gg=0; gg<8; gg++) acc[gg] += w*qsr[gg][k];
  }
  const float* wr2 = Whh + (size_t)j*64;
  for (int k=0; k<64; k++){
    float w = wr2[k];
    #pragma unroll
    for (int gg=0; gg<8; gg++) acc[gg] += w*hlr[gg][k];
  }
  #pragma unroll
  for (int gg=0; gg<8; gg++) gat[gg][j] = acc[gg];
  __syncthreads();
  #pragma unroll
  for (int it=0; it<2; ++it){
    int idx = it*256 + tid;
    int gg = idx>>6, d = idx&63;
    int graph = g0+gg;
    float ig = sigmoidf_(gat[gg][d]);
    float fg = sigmoidf_(gat[gg][64+d]);
    float gv = tanhf(gat[gg][128+d]);
    float og = sigmoidf_(gat[gg][192+d]);
    float c = fg*cl[(size_t)graph*64+d] + ig*gv;
    float h = og*tanhf(c);
    cl[(size_t)graph*64+d] = c;
    hl[(size_t)graph*64+d] = h;
    qs[(size_t)graph*128+d] = h;   // q part of q_star
  }
}

// ---------------- attention pooling, one online-softmax sweep ----------------
__global__ void k_attn(const float* __restrict__ out, const int* __restrict__ goff,
                       const float* __restrict__ hl, float* __restrict__ qs){
  __shared__ float redm[4], redd[4];
  __shared__ float redr[4][64];
  int g = blockIdx.x;
  int tid = threadIdx.x, lane = tid&63, wv = tid>>6;
  int s = goff[g], e = goff[g+1];
  float q = hl[(size_t)g*64+lane];
  float m = -3.0e38f, denom = 0.f, racc = 0.f;
  for (int n=s+wv; n<e; n+=4){
    float v = out[(size_t)n*64+lane];
    float p = v*q;
    #pragma unroll
    for (int off=32; off>=1; off>>=1) p += __shfl_xor(p, off, 64);
    if (p > m){                      // wave-uniform branch
      float sc = __expf(m - p);      // first time: exp(-huge) -> 0
      denom *= sc; racc *= sc; m = p;
    }
    float w = __expf(p - m);
    denom += w; racc += w*v;
  }
  if (lane==0){ redm[wv] = m; redd[wv] = denom; }
  redr[wv][lane] = racc;
  __syncthreads();
  if (wv==0){
    float m0=redm[0], m1=redm[1], m2=redm[2], m3=redm[3];
    float mm = fmaxf(fmaxf(m0,m1), fmaxf(m2,m3));
    float s0=__expf(m0-mm), s1=__expf(m1-mm), s2=__expf(m2-mm), s3=__expf(m3-mm);
    float dt = redd[0]*s0 + redd[1]*s1 + redd[2]*s2 + redd[3]*s3;
    float rs = redr[0][lane]*s0 + redr[1][lane]*s1 + redr[2][lane]*s2 + redr[3][lane]*s3;
    qs[(size_t)g*128+64+lane] = (dt > 0.f) ? rs/dt : 0.f;
  }
}

// ---------------- final MLP ----------------
__global__ void k_final(const float* __restrict__ qs, const float* __restrict__ W1,
                        const float* __restrict__ b1, const float* __restrict__ W2,
                        const float* __restrict__ b2, float* __restrict__ outy){
  __shared__ float qsr[128];
  __shared__ float yy[64];
  int g = blockIdx.x; int t = threadIdx.x;  // 64 threads
  qsr[t]    = qs[(size_t)g*128 + t];
  qsr[64+t] = qs[(size_t)g*128 + 64 + t];
  __syncthreads();
  float acc = b1[t];
  for (int k=0; k<128; k++) acc += qsr[k]*W1[k*64+t];
  yy[t] = fmaxf(acc, 0.f);
  __syncthreads();
  if (t < 12){
    float a2 = b2[t];
    for (int k=0; k<64; k++) a2 += yy[k]*W2[k*12+t];
    outy[(size_t)g*12 + t] = a2;
  }
}

extern "C" void kernel_launch(void* const* d_in, const int* in_sizes, int n_in,
                              void* d_out, int out_size, void* d_ws, size_t ws_size,
                              hipStream_t stream){
  const float* x    = (const float*)d_in[0];
  const int*   ei   = (const int*)d_in[1];
  const int*   batch= (const int*)d_in[2];
  const float* W0   = (const float*)d_in[3];
  const float* b0   = (const float*)d_in[4];
  const float* Wc   = (const float*)d_in[5];
  const float* bc   = (const float*)d_in[6];
  const float* Wih  = (const float*)d_in[7];
  const float* Whh  = (const float*)d_in[8];
  const float* bih  = (const float*)d_in[9];
  const float* bhh  = (const float*)d_in[10];
  const float* W1   = (const float*)d_in[11];
  const float* b1   = (const float*)d_in[12];
  const float* W2   = (const float*)d_in[13];
  const float* b2   = (const float*)d_in[14];
  float* yout = (float*)d_out;

  const int N = in_sizes[0]/15;
  const int E = in_sizes[1]/2;
  const int B = out_size/12;
  const int NBK = (N + (1<<BKT_SHIFT) - 1) >> BKT_SHIFT;
  const int* row = ei;       // sources
  const int* col = ei + E;   // targets

  char* ws = (char*)d_ws;
  size_t off = 0;
  auto alloc = [&](size_t bytes)->void*{
    void* p = ws + off; off = (off + bytes + 255) & ~(size_t)255; return p;
  };
  int*      deg     = (int*)     alloc((size_t)N*4);
  int*      rowptr  = (int*)     alloc((size_t)(N+1)*4);
  int*      partial = (int*)     alloc((size_t)N*4);
  int*      bsum    = (int*)     alloc(4096);
  int*      bcur    = (int*)     alloc((size_t)NBK*BCUR_PAD*4);
  unsigned* pairs   = (unsigned*)alloc((size_t)E*4);
  int*      csr     = (int*)     alloc((size_t)E*4);
  float*    dinv    = (float*)   alloc((size_t)N*4);
  float*    nodef   = (float*)   alloc((size_t)N*ND*4);
  __half*   gbuf    = (__half*)  alloc((size_t)N*ND*2);
  int*      goff    = (int*)     alloc((size_t)(B+1)*4);
  float*    hl      = (float*)   alloc((size_t)B*64*4);
  float*    cl      = (float*)   alloc((size_t)B*64*4);
  float*    qs      = (float*)   alloc((size_t)B*128*4);
  (void)ws_size; (void)n_in;

  hipMemsetAsync(deg,  0, (size_t)N*4, stream);
  hipMemsetAsync(hl,   0, (size_t)B*64*4, stream);
  hipMemsetAsync(cl,   0, (size_t)B*64*4, stream);
  hipMemsetAsync(qs,   0, (size_t)B*128*4, stream);

  k_degree<<<(E+255)/256, 256, 0, stream>>>(col, deg, E);
  k_dinv  <<<(N+255)/256, 256, 0, stream>>>(deg, dinv, N);
  int nb = (N + SCAN_BLK - 1)/SCAN_BLK;
  k_scan1<<<nb, SCAN_BLK, 0, stream>>>(deg, partial, bsum, N);
  k_scan2<<<1, 64, 0, stream>>>(bsum, nb);
  k_scan3<<<nb, SCAN_BLK, 0, stream>>>(partial, bsum, rowptr, N);
  k_bcinit<<<(NBK+255)/256, 256, 0, stream>>>(rowptr, bcur, NBK, N);
  k_stage <<<(E+255)/256, 256, 0, stream>>>(row, col, bcur, pairs, E);
  k_place <<<NBK, 256, 0, stream>>>(pairs, rowptr, csr, N);

  k_input<<<(N+3)/4, 256, 0, stream>>>(x, W0, b0, nodef, N);
  for (int s6=0; s6<6; ++s6){
    k_transform<<<(N+15)/16, 256, 0, stream>>>(nodef, Wc, dinv, gbuf, N);
    k_gather   <<<(N+3)/4,   256, 0, stream>>>((const __half2*)gbuf, rowptr, csr, dinv, bc, nodef, N);
  }

  k_goff<<<(N+255)/256, 256, 0, stream>>>(batch, goff, N, B);
  for (int s6=0; s6<6; ++s6){
    k_lstm<<<B/8, 256, 0, stream>>>(Wih, Whh, bih, bhh, qs, hl, cl);
    k_attn<<<B,   256, 0, stream>>>(nodef, goff, hl, qs);
  }
  k_final<<<B, 64, 0, stream>>>(qs, W1, b1, W2, b2, yout);
}

// Round 6
// 1180.223 us; speedup vs baseline: 2.5294x; 1.1522x over previous
//
#include <hip/hip_runtime.h>
#include <hip/hip_fp16.h>
#include <math.h>

#define ND 64
constexpr int SCAN_BLK = 1024;
constexpr int BKT_SHIFT = 9;          // 512 nodes per bucket (196 buckets); src<<9 fits u32 (N < 2^17)
constexpr int BKT_MASK = (1 << BKT_SHIFT) - 1;
constexpr int BCUR_PAD = 16;          // ints -> 64 B per cursor
constexpr int STG_TILE = 8192;        // edges per stage block

__device__ __forceinline__ float sigmoidf_(float x){ return 1.f/(1.f+__expf(-x)); }

// ---------------- CSR build ----------------
__global__ void k_degree(const int* __restrict__ col, int* __restrict__ deg, int E){
  int i = blockIdx.x*blockDim.x + threadIdx.x;
  if (i < E) atomicAdd(&deg[col[i]], 1);
}

__global__ void k_dinv(const int* __restrict__ deg, float* __restrict__ dinv, int N){
  int i = blockIdx.x*blockDim.x + threadIdx.x;
  if (i < N) dinv[i] = rsqrtf((float)(deg[i] + 1));   // +1 = self loop
}

__global__ void k_scan1(const int* __restrict__ cnt, int* __restrict__ partial,
                        int* __restrict__ bsum, int n){
  __shared__ int tmp[SCAN_BLK];
  int i = blockIdx.x*SCAN_BLK + threadIdx.x;
  int v = (i<n) ? cnt[i] : 0;
  tmp[threadIdx.x] = v; __syncthreads();
  for (int off=1; off<SCAN_BLK; off<<=1){
    int t = (threadIdx.x>=off) ? tmp[threadIdx.x-off] : 0;
    __syncthreads();
    tmp[threadIdx.x] += t;
    __syncthreads();
  }
  if (i<n) partial[i] = tmp[threadIdx.x];
  if (threadIdx.x==SCAN_BLK-1) bsum[blockIdx.x] = tmp[threadIdx.x];
}

__global__ void k_scan2(int* bsum, int nb){
  if (threadIdx.x==0 && blockIdx.x==0){
    int acc=0;
    for (int b=0;b<nb;b++){ int v=bsum[b]; bsum[b]=acc; acc+=v; }
  }
}

// standard rowptr: rowptr[0]=0, rowptr[i+1]=incl_scan(deg)[i]  (rowptr[N]=E)
__global__ void k_scan3(const int* __restrict__ partial, const int* __restrict__ bsum,
                        int* __restrict__ rowptr, int n){
  int i = blockIdx.x*SCAN_BLK + threadIdx.x;
  if (i<n){
    rowptr[i+1] = partial[i] + bsum[blockIdx.x];
    if (i==0) rowptr[0] = 0;
  }
}

__global__ void k_bcinit(const int* __restrict__ rowptr, int* __restrict__ bcur,
                         int NBK, int N){
  int b = blockIdx.x*blockDim.x + threadIdx.x;
  if (b < NBK){
    int node = b << BKT_SHIFT;
    bcur[b*BCUR_PAD] = rowptr[node < N ? node : N];
  }
}

// stage pass: per-block LDS histogram over buckets -> ONE global atomic per
// (block,bucket) chunk reservation -> contiguous run writes (kills the 12x
// write amplification of per-edge device-scope cursor atomics)
__global__ void k_stage2(const int* __restrict__ row, const int* __restrict__ col,
                         int* __restrict__ bcur, unsigned* __restrict__ pairs,
                         int E, int NBK){
  __shared__ int lhist[512];
  __shared__ int lbase[512];
  int t0 = blockIdx.x * STG_TILE;
  int t1 = t0 + STG_TILE; if (t1 > E) t1 = E;
  for (int i = threadIdx.x; i < NBK; i += 256) lhist[i] = 0;
  __syncthreads();
  for (int i = t0 + threadIdx.x; i < t1; i += 256)
    atomicAdd(&lhist[col[i] >> BKT_SHIFT], 1);
  __syncthreads();
  for (int i = threadIdx.x; i < NBK; i += 256){
    int c = lhist[i];
    lbase[i] = (c > 0) ? atomicAdd(&bcur[i*BCUR_PAD], c) : 0;
    lhist[i] = 0;
  }
  __syncthreads();
  for (int i = t0 + threadIdx.x; i < t1; i += 256){
    int d = col[i];
    int b = d >> BKT_SHIFT;
    int pos = lbase[b] + atomicAdd(&lhist[b], 1);
    pairs[pos] = ((unsigned)row[i] << BKT_SHIFT) | (unsigned)(d & BKT_MASK);
  }
}

// place pass: one block per bucket; LDS cursors; csr writes confined to ~64KB window
__global__ void k_place(const unsigned* __restrict__ pairs, const int* __restrict__ rowptr,
                        int* __restrict__ csr, int N){
  __shared__ int lcur[1 << BKT_SHIFT];
  int b = blockIdx.x;
  int base = b << BKT_SHIFT;
  int nend = base + (1 << BKT_SHIFT); if (nend > N) nend = N;
  int cnt = nend - base;
  for (int c = threadIdx.x; c < cnt; c += 256) lcur[c] = rowptr[base + c];
  __syncthreads();
  int s = rowptr[base], e = rowptr[nend];
  for (int i = s + threadIdx.x; i < e; i += 256){
    unsigned p = pairs[i];
    int pos = atomicAdd(&lcur[p & BKT_MASK], 1);
    csr[pos] = (int)(p >> BKT_SHIFT);
  }
}

// ---------------- input MLP: s0 = fp16( dinv * relu(x @ W0 + b0) ) ----------------
__global__ void k_input(const float* __restrict__ x, const float* __restrict__ W0,
                        const float* __restrict__ b0, const float* __restrict__ dinv,
                        __half* __restrict__ s, int N){
  __shared__ float w0s[15*ND];
  __shared__ float b0s[ND];
  int tid = threadIdx.x;
  for (int i=tid; i<15*ND; i+=256) w0s[i] = W0[i];
  if (tid < ND) b0s[tid] = b0[tid];
  __syncthreads();
  int node = blockIdx.x*4 + (tid>>6);
  int f = tid & 63;
  if (node < N){
    float acc = b0s[f];
    const float* xr = x + (size_t)node*15;
    #pragma unroll
    for (int k=0;k<15;k++) acc += xr[k]*w0s[k*ND+f];
    s[(size_t)node*ND+f] = __float2half_rn(dinv[node]*fmaxf(acc, 0.f));
  }
}

// ---------------- fused propagation step ----------------
// s_new[v] = fp16( dinv_v * relu( dinv_v*(sum_u s_old[u] + s_old[v]) @ Wc + bc ) )
// (identity: sum dinv_u dinv_v (out_u@Wc) = dinv_v*(sum dinv_u out_u)@Wc)
// gather phase: 4 waves x 4 nodes, 2 src rows per unrolled step (half2 lanes)
// GEMM phase: round-2 scalar-LDS inner loop (proven fast)
__global__ void k_prop(const __half2* __restrict__ s2, const int* __restrict__ rowptr,
                       const int* __restrict__ csr, const float* __restrict__ dinv,
                       const float* __restrict__ Wc, const float* __restrict__ bc,
                       __half* __restrict__ s_new, float* __restrict__ outf,
                       int N, int wout){
  __shared__ float wcs[ND*ND];
  __shared__ float xs[16][ND];
  __shared__ float bcs[ND];
  int tid = threadIdx.x;
  for (int i=tid; i<ND*ND; i+=256) wcs[i] = Wc[i];
  if (tid < ND) bcs[tid] = bc[tid];
  int nb = blockIdx.x*16;
  int wv = tid>>6, lane = tid&63, half = lane>>5, le = lane&31;

  for (int q=0; q<4; ++q){
    int node = nb + wv*4 + q;
    float sx = 0.f, sy = 0.f;
    if (node < N){
      int s = rowptr[node], e = rowptr[node+1];
      float ax0=0.f,ax1=0.f,ax2=0.f,ax3=0.f,ax4=0.f,ax5=0.f,ax6=0.f,ax7=0.f;
      float ay0=0.f,ay1=0.f,ay2=0.f,ay3=0.f,ay4=0.f,ay5=0.f,ay6=0.f,ay7=0.f;
      int i = s;
      for (; i + 16 <= e; i += 16){
        int s0 = csr[i + 0 + half];
        int s1 = csr[i + 2 + half];
        int s2i= csr[i + 4 + half];
        int s3 = csr[i + 6 + half];
        int s4 = csr[i + 8 + half];
        int s5 = csr[i +10 + half];
        int s6 = csr[i +12 + half];
        int s7 = csr[i +14 + half];
        float2 f0 = __half22float2(s2[(size_t)s0*32 + le]);
        float2 f1 = __half22float2(s2[(size_t)s1*32 + le]);
        float2 f2 = __half22float2(s2[(size_t)s2i*32 + le]);
        float2 f3 = __half22float2(s2[(size_t)s3*32 + le]);
        float2 f4 = __half22float2(s2[(size_t)s4*32 + le]);
        float2 f5 = __half22float2(s2[(size_t)s5*32 + le]);
        float2 f6 = __half22float2(s2[(size_t)s6*32 + le]);
        float2 f7 = __half22float2(s2[(size_t)s7*32 + le]);
        ax0 += f0.x; ay0 += f0.y;
        ax1 += f1.x; ay1 += f1.y;
        ax2 += f2.x; ay2 += f2.y;
        ax3 += f3.x; ay3 += f3.y;
        ax4 += f4.x; ay4 += f4.y;
        ax5 += f5.x; ay5 += f5.y;
        ax6 += f6.x; ay6 += f6.y;
        ax7 += f7.x; ay7 += f7.y;
      }
      for (; i + 2 <= e; i += 2){
        int src = csr[i + half];
        float2 f = __half22float2(s2[(size_t)src*32 + le]);
        ax0 += f.x; ay0 += f.y;
      }
      if (half == 0){
        if (i < e){
          float2 f = __half22float2(s2[(size_t)csr[i]*32 + le]);
          ax1 += f.x; ay1 += f.y;
        }
        float2 f = __half22float2(s2[(size_t)node*32 + le]);   // self loop
        ax2 += f.x; ay2 += f.y;
      }
      sx = ((ax0+ax1)+(ax2+ax3)) + ((ax4+ax5)+(ax6+ax7));
      sy = ((ay0+ay1)+(ay2+ay3)) + ((ay4+ay5)+(ay6+ay7));
      sx += __shfl_xor(sx, 32, 64);
      sy += __shfl_xor(sy, 32, 64);
    }
    if (half == 0){
      xs[wv*4+q][2*le]   = sx;
      xs[wv*4+q][2*le+1] = sy;
    }
  }
  __syncthreads();

  int f = tid&63, nq = tid>>6;
  float acc0=0.f, acc1=0.f, acc2=0.f, acc3=0.f;
  #pragma unroll 16
  for (int k=0;k<ND;k++){
    float w = wcs[k*ND+f];
    acc0 += w*xs[nq*4+0][k];
    acc1 += w*xs[nq*4+1][k];
    acc2 += w*xs[nq*4+2][k];
    acc3 += w*xs[nq*4+3][k];
  }
  int n0 = nb + nq*4;
  float bcf = bcs[f];
  #pragma unroll
  for (int j=0; j<4; ++j){
    int node = n0 + j;
    if (node < N){
      float a = (j==0)?acc0:(j==1)?acc1:(j==2)?acc2:acc3;
      float dn = dinv[node];
      float r = fmaxf(dn*a + bcf, 0.f);
      s_new[(size_t)node*ND+f] = __float2half_rn(dn*r);
      if (wout) outf[(size_t)node*ND+f] = r;
    }
  }
}

// ---------------- per-graph contiguous ranges (batch is sorted) ----------------
__global__ void k_goff(const int* __restrict__ batch, int* __restrict__ goff, int N, int B){
  int i = blockIdx.x*blockDim.x + threadIdx.x;
  if (i >= N) return;
  int b = batch[i];
  if (i == 0){ for (int g2=0; g2<=b; ++g2) goff[g2]=0; }
  else {
    int bp = batch[i-1];
    for (int g2=bp+1; g2<=b; ++g2) goff[g2]=i;
  }
  if (i == N-1){ for (int g2=b+1; g2<=B; ++g2) goff[g2]=N; }
}

// ---------------- LSTM step (8 graphs per block) ----------------
__global__ void k_lstm(const float* __restrict__ Wih, const float* __restrict__ Whh,
                       const float* __restrict__ bih, const float* __restrict__ bhh,
                       float* __restrict__ qs, float* __restrict__ hl, float* __restrict__ cl){
  __shared__ float qsr[8][128];
  __shared__ float hlr[8][64];
  __shared__ float gat[8][256];
  int tid = threadIdx.x;
  int g0 = blockIdx.x*8;
  for (int i=tid; i<8*128; i+=256){ int gg=i>>7, k=i&127; qsr[gg][k] = qs[(size_t)(g0+gg)*128+k]; }
  for (int i=tid; i<8*64;  i+=256){ int gg=i>>6, k=i&63;  hlr[gg][k] = hl[(size_t)(g0+gg)*64+k]; }
  __syncthreads();
  int j = tid;  // gate index 0..255
  float bb = bih[j] + bhh[j];
  float acc[8];
  #pragma unroll
  for (int gg=0; gg<8; gg++) acc[gg] = bb;
  const float* wr = Wih + (size_t)j*128;
  for (int k=0; k<128; k++){
    float w = wr[k];
    #pragma unroll
    for (int gg=0; gg<8; gg++) acc[gg] += w*qsr[gg][k];
  }
  const float* wr2 = Whh + (size_t)j*64;
  for (int k=0; k<64; k++){
    float w = wr2[k];
    #pragma unroll
    for (int gg=0; gg<8; gg++) acc[gg] += w*hlr[gg][k];
  }
  #pragma unroll
  for (int gg=0; gg<8; gg++) gat[gg][j] = acc[gg];
  __syncthreads();
  #pragma unroll
  for (int it=0; it<2; ++it){
    int idx = it*256 + tid;
    int gg = idx>>6, d = idx&63;
    int graph = g0+gg;
    float ig = sigmoidf_(gat[gg][d]);
    float fg = sigmoidf_(gat[gg][64+d]);
    float gv = tanhf(gat[gg][128+d]);
    float og = sigmoidf_(gat[gg][192+d]);
    float c = fg*cl[(size_t)graph*64+d] + ig*gv;
    float h = og*tanhf(c);
    cl[(size_t)graph*64+d] = c;
    hl[(size_t)graph*64+d] = h;
    qs[(size_t)graph*128+d] = h;   // q part of q_star
  }
}

// ---------------- attention pooling, one online-softmax sweep ----------------
__global__ void k_attn(const float* __restrict__ out, const int* __restrict__ goff,
                       const float* __restrict__ hl, float* __restrict__ qs){
  __shared__ float redm[4], redd[4];
  __shared__ float redr[4][64];
  int g = blockIdx.x;
  int tid = threadIdx.x, lane = tid&63, wv = tid>>6;
  int s = goff[g], e = goff[g+1];
  float q = hl[(size_t)g*64+lane];
  float m = -3.0e38f, denom = 0.f, racc = 0.f;
  for (int n=s+wv; n<e; n+=4){
    float v = out[(size_t)n*64+lane];
    float p = v*q;
    #pragma unroll
    for (int off=32; off>=1; off>>=1) p += __shfl_xor(p, off, 64);
    if (p > m){                      // wave-uniform branch
      float sc = __expf(m - p);      // first time: exp(-huge) -> 0
      denom *= sc; racc *= sc; m = p;
    }
    float w = __expf(p - m);
    denom += w; racc += w*v;
  }
  if (lane==0){ redm[wv] = m; redd[wv] = denom; }
  redr[wv][lane] = racc;
  __syncthreads();
  if (wv==0){
    float m0=redm[0], m1=redm[1], m2=redm[2], m3=redm[3];
    float mm = fmaxf(fmaxf(m0,m1), fmaxf(m2,m3));
    float s0=__expf(m0-mm), s1=__expf(m1-mm), s2=__expf(m2-mm), s3=__expf(m3-mm);
    float dt = redd[0]*s0 + redd[1]*s1 + redd[2]*s2 + redd[3]*s3;
    float rs = redr[0][lane]*s0 + redr[1][lane]*s1 + redr[2][lane]*s2 + redr[3][lane]*s3;
    qs[(size_t)g*128+64+lane] = (dt > 0.f) ? rs/dt : 0.f;
  }
}

// ---------------- final MLP ----------------
__global__ void k_final(const float* __restrict__ qs, const float* __restrict__ W1,
                        const float* __restrict__ b1, const float* __restrict__ W2,
                        const float* __restrict__ b2, float* __restrict__ outy){
  __shared__ float qsr[128];
  __shared__ float yy[64];
  int g = blockIdx.x; int t = threadIdx.x;  // 64 threads
  qsr[t]    = qs[(size_t)g*128 + t];
  qsr[64+t] = qs[(size_t)g*128 + 64 + t];
  __syncthreads();
  float acc = b1[t];
  for (int k=0; k<128; k++) acc += qsr[k]*W1[k*64+t];
  yy[t] = fmaxf(acc, 0.f);
  __syncthreads();
  if (t < 12){
    float a2 = b2[t];
    for (int k=0; k<64; k++) a2 += yy[k]*W2[k*12+t];
    outy[(size_t)g*12 + t] = a2;
  }
}

extern "C" void kernel_launch(void* const* d_in, const int* in_sizes, int n_in,
                              void* d_out, int out_size, void* d_ws, size_t ws_size,
                              hipStream_t stream){
  const float* x    = (const float*)d_in[0];
  const int*   ei   = (const int*)d_in[1];
  const int*   batch= (const int*)d_in[2];
  const float* W0   = (const float*)d_in[3];
  const float* b0   = (const float*)d_in[4];
  const float* Wc   = (const float*)d_in[5];
  const float* bc   = (const float*)d_in[6];
  const float* Wih  = (const float*)d_in[7];
  const float* Whh  = (const float*)d_in[8];
  const float* bih  = (const float*)d_in[9];
  const float* bhh  = (const float*)d_in[10];
  const float* W1   = (const float*)d_in[11];
  const float* b1   = (const float*)d_in[12];
  const float* W2   = (const float*)d_in[13];
  const float* b2   = (const float*)d_in[14];
  float* yout = (float*)d_out;

  const int N = in_sizes[0]/15;
  const int E = in_sizes[1]/2;
  const int B = out_size/12;
  const int NBK = (N + (1<<BKT_SHIFT) - 1) >> BKT_SHIFT;
  const int* row = ei;       // sources
  const int* col = ei + E;   // targets

  char* ws = (char*)d_ws;
  size_t off = 0;
  auto alloc = [&](size_t bytes)->void*{
    void* p = ws + off; off = (off + bytes + 255) & ~(size_t)255; return p;
  };
  int*      deg     = (int*)     alloc((size_t)N*4);
  int*      rowptr  = (int*)     alloc((size_t)(N+1)*4);
  int*      partial = (int*)     alloc((size_t)N*4);
  int*      bsum    = (int*)     alloc(4096);
  int*      bcur    = (int*)     alloc((size_t)NBK*BCUR_PAD*4);
  unsigned* pairs   = (unsigned*)alloc((size_t)E*4);
  int*      csr     = (int*)     alloc((size_t)E*4);
  float*    dinv    = (float*)   alloc((size_t)N*4);
  float*    nodef   = (float*)   alloc((size_t)N*ND*4);
  __half*   s_a     = (__half*)  alloc((size_t)N*ND*2);
  __half*   s_b     = (__half*)  alloc((size_t)N*ND*2);
  int*      goff    = (int*)     alloc((size_t)(B+1)*4);
  float*    hl      = (float*)   alloc((size_t)B*64*4);
  float*    cl      = (float*)   alloc((size_t)B*64*4);
  float*    qs      = (float*)   alloc((size_t)B*128*4);
  (void)ws_size; (void)n_in;

  hipMemsetAsync(deg,  0, (size_t)N*4, stream);
  hipMemsetAsync(hl,   0, (size_t)B*64*4, stream);
  hipMemsetAsync(cl,   0, (size_t)B*64*4, stream);
  hipMemsetAsync(qs,   0, (size_t)B*128*4, stream);

  k_degree<<<(E+255)/256, 256, 0, stream>>>(col, deg, E);
  k_dinv  <<<(N+255)/256, 256, 0, stream>>>(deg, dinv, N);
  int nb = (N + SCAN_BLK - 1)/SCAN_BLK;
  k_scan1<<<nb, SCAN_BLK, 0, stream>>>(deg, partial, bsum, N);
  k_scan2<<<1, 64, 0, stream>>>(bsum, nb);
  k_scan3<<<nb, SCAN_BLK, 0, stream>>>(partial, bsum, rowptr, N);
  k_bcinit<<<(NBK+255)/256, 256, 0, stream>>>(rowptr, bcur, NBK, N);
  int nstg = (E + STG_TILE - 1)/STG_TILE;
  k_stage2<<<nstg, 256, 0, stream>>>(row, col, bcur, pairs, E, NBK);
  k_place <<<NBK, 256, 0, stream>>>(pairs, rowptr, csr, N);

  k_input<<<(N+3)/4, 256, 0, stream>>>(x, W0, b0, dinv, s_a, N);
  __half* scur = s_a; __half* snxt = s_b;
  for (int s6=0; s6<6; ++s6){
    k_prop<<<(N+15)/16, 256, 0, stream>>>((const __half2*)scur, rowptr, csr, dinv,
                                          Wc, bc, snxt, nodef, N, (s6==5)?1:0);
    __half* t = scur; scur = snxt; snxt = t;
  }

  k_goff<<<(N+255)/256, 256, 0, stream>>>(batch, goff, N, B);
  for (int s6=0; s6<6; ++s6){
    k_lstm<<<B/8, 256, 0, stream>>>(Wih, Whh, bih, bhh, qs, hl, cl);
    k_attn<<<B,   256, 0, stream>>>(nodef, goff, hl, qs);
  }
  k_final<<<B, 64, 0, stream>>>(qs, W1, b1, W2, b2, yout);
}

// Round 7
// 1062.930 us; speedup vs baseline: 2.8085x; 1.1103x over previous
//
#include <hip/hip_runtime.h>
#include <hip/hip_fp16.h>
#include <math.h>

#define ND 64
constexpr int BKT_SHIFT = 9;          // 512 nodes per bucket; NBK = ceil(100k/512) = 196 <= 256
constexpr int BKT_MASK = (1 << BKT_SHIFT) - 1;
constexpr int BCUR_PAD = 16;          // ints -> 64 B per cursor
constexpr int STG_TILE = 8192;        // edges per stage block

__device__ __forceinline__ float sigmoidf_(float x){ return 1.f/(1.f+__expf(-x)); }

// ---------------- bucket-hierarchical CSR build ----------------
// pass 0: per-block LDS histogram of edges per coarse bucket -> ~196 global
// atomics per block instead of 3.2M random 4B global atomics (which write-
// amplified 250x: 100MB WRITE_SIZE for a 400KB deg array in round 6)
__global__ void k_bhist(const int* __restrict__ col, int* __restrict__ bgcnt,
                        int E, int NBK){
  __shared__ int lhist[512];
  int t0 = blockIdx.x * STG_TILE;
  int t1 = t0 + STG_TILE; if (t1 > E) t1 = E;
  for (int i = threadIdx.x; i < NBK; i += 256) lhist[i] = 0;
  __syncthreads();
  for (int i = t0 + threadIdx.x; i < t1; i += 256)
    atomicAdd(&lhist[col[i] >> BKT_SHIFT], 1);
  __syncthreads();
  for (int i = threadIdx.x; i < NBK; i += 256)
    if (lhist[i] > 0) atomicAdd(&bgcnt[i], lhist[i]);
}

// pass 0b: one-block exclusive scan of bucket counts (NBK <= 256)
__global__ void k_bscan(const int* __restrict__ bgcnt, int* __restrict__ bstart,
                        int* __restrict__ rowptr, int NBK, int E, int N){
  __shared__ int tmp[256];
  int t = threadIdx.x;
  int v = (t < NBK) ? bgcnt[t] : 0;
  tmp[t] = v; __syncthreads();
  for (int off=1; off<256; off<<=1){
    int u = (t>=off) ? tmp[t-off] : 0;
    __syncthreads();
    tmp[t] += u;
    __syncthreads();
  }
  if (t <= NBK) bstart[t] = (t==0) ? 0 : tmp[t-1];
  if (t == 0) rowptr[N] = E;
}

__global__ void k_bcinit(const int* __restrict__ bstart, int* __restrict__ bcur, int NBK){
  int b = blockIdx.x*blockDim.x + threadIdx.x;
  if (b < NBK) bcur[b*BCUR_PAD] = bstart[b];
}

// pass 1: stage packed (src<<9 | dst&511) into buckets; per-block LDS histogram
// -> ONE global atomic chunk reservation per (block,bucket) -> contiguous writes
__global__ void k_stage2(const int* __restrict__ row, const int* __restrict__ col,
                         int* __restrict__ bcur, unsigned* __restrict__ pairs,
                         int E, int NBK){
  __shared__ int lhist[512];
  __shared__ int lbase[512];
  int t0 = blockIdx.x * STG_TILE;
  int t1 = t0 + STG_TILE; if (t1 > E) t1 = E;
  for (int i = threadIdx.x; i < NBK; i += 256) lhist[i] = 0;
  __syncthreads();
  for (int i = t0 + threadIdx.x; i < t1; i += 256)
    atomicAdd(&lhist[col[i] >> BKT_SHIFT], 1);
  __syncthreads();
  for (int i = threadIdx.x; i < NBK; i += 256){
    int c = lhist[i];
    lbase[i] = (c > 0) ? atomicAdd(&bcur[i*BCUR_PAD], c) : 0;
    lhist[i] = 0;
  }
  __syncthreads();
  for (int i = t0 + threadIdx.x; i < t1; i += 256){
    int d = col[i];
    int b = d >> BKT_SHIFT;
    int pos = lbase[b] + atomicAdd(&lhist[b], 1);
    pairs[pos] = ((unsigned)row[i] << BKT_SHIFT) | (unsigned)(d & BKT_MASK);
  }
}

// pass 2: one block per bucket. Local LDS degree histogram -> local scan ->
// writes rowptr + dinv for its 512 nodes -> scatters csr into its ~64KB window.
// All per-node atomics are LDS-scope; no N-wide global histogram/scan needed.
__global__ void k_place(const unsigned* __restrict__ pairs, const int* __restrict__ bstart,
                        int* __restrict__ rowptr, float* __restrict__ dinv,
                        int* __restrict__ csr, int N){
  __shared__ int h[1 << BKT_SHIFT];      // histogram -> later: cursors
  __shared__ int excl[1 << BKT_SHIFT];   // exclusive offsets
  __shared__ int tsum[256];
  int b = blockIdx.x;
  int base = b << BKT_SHIFT;
  int nend = base + (1 << BKT_SHIFT); if (nend > N) nend = N;
  int cnt = nend - base;
  int t = threadIdx.x;
  int s = bstart[b], e = bstart[b+1];

  h[2*t] = 0; h[2*t+1] = 0;
  __syncthreads();
  for (int i = s + t; i < e; i += 256)
    atomicAdd(&h[pairs[i] & BKT_MASK], 1);
  __syncthreads();
  // block scan over 512 counters (2 per thread)
  int a0 = h[2*t], a1 = h[2*t+1];
  tsum[t] = a0 + a1;
  __syncthreads();
  for (int off=1; off<256; off<<=1){
    int u = (t>=off) ? tsum[t-off] : 0;
    __syncthreads();
    tsum[t] += u;
    __syncthreads();
  }
  int base0 = (t==0) ? 0 : tsum[t-1];
  excl[2*t]   = base0;
  excl[2*t+1] = base0 + a0;
  __syncthreads();
  // emit rowptr + dinv; convert h into global cursors
  for (int c = t; c < cnt; c += 256){
    int deg = h[c];
    rowptr[base + c] = s + excl[c];
    dinv[base + c] = rsqrtf((float)(deg + 1));   // +1 = self loop
  }
  __syncthreads();
  for (int c = t; c < cnt; c += 256) h[c] = s + excl[c];
  __syncthreads();
  // scatter
  for (int i = s + t; i < e; i += 256){
    unsigned p = pairs[i];
    int pos = atomicAdd(&h[p & BKT_MASK], 1);
    csr[pos] = (int)(p >> BKT_SHIFT);
  }
}

// ---------------- input MLP: s0 = fp16( dinv * relu(x @ W0 + b0) ) ----------------
__global__ void k_input(const float* __restrict__ x, const float* __restrict__ W0,
                        const float* __restrict__ b0, const float* __restrict__ dinv,
                        __half* __restrict__ s, int N){
  __shared__ float w0s[15*ND];
  __shared__ float b0s[ND];
  int tid = threadIdx.x;
  for (int i=tid; i<15*ND; i+=256) w0s[i] = W0[i];
  if (tid < ND) b0s[tid] = b0[tid];
  __syncthreads();
  int node = blockIdx.x*4 + (tid>>6);
  int f = tid & 63;
  if (node < N){
    float acc = b0s[f];
    const float* xr = x + (size_t)node*15;
    #pragma unroll
    for (int k=0;k<15;k++) acc += xr[k]*w0s[k*ND+f];
    s[(size_t)node*ND+f] = __float2half_rn(dinv[node]*fmaxf(acc, 0.f));
  }
}

// ---------------- fused propagation step ----------------
// s_new[v] = fp16( dinv_v * relu( dinv_v*(sum_u s_old[u] + s_old[v]) @ Wc + bc ) )
__global__ void k_prop(const __half2* __restrict__ s2, const int* __restrict__ rowptr,
                       const int* __restrict__ csr, const float* __restrict__ dinv,
                       const float* __restrict__ Wc, const float* __restrict__ bc,
                       __half* __restrict__ s_new, float* __restrict__ outf,
                       int N, int wout){
  __shared__ float wcs[ND*ND];
  __shared__ float xs[16][ND];
  __shared__ float bcs[ND];
  int tid = threadIdx.x;
  for (int i=tid; i<ND*ND; i+=256) wcs[i] = Wc[i];
  if (tid < ND) bcs[tid] = bc[tid];
  int nb = blockIdx.x*16;
  int wv = tid>>6, lane = tid&63, half = lane>>5, le = lane&31;

  for (int q=0; q<4; ++q){
    int node = nb + wv*4 + q;
    float sx = 0.f, sy = 0.f;
    if (node < N){
      int s = rowptr[node], e = rowptr[node+1];
      float ax0=0.f,ax1=0.f,ax2=0.f,ax3=0.f,ax4=0.f,ax5=0.f,ax6=0.f,ax7=0.f;
      float ay0=0.f,ay1=0.f,ay2=0.f,ay3=0.f,ay4=0.f,ay5=0.f,ay6=0.f,ay7=0.f;
      int i = s;
      for (; i + 16 <= e; i += 16){
        int s0 = csr[i + 0 + half];
        int s1 = csr[i + 2 + half];
        int s2i= csr[i + 4 + half];
        int s3 = csr[i + 6 + half];
        int s4 = csr[i + 8 + half];
        int s5 = csr[i +10 + half];
        int s6 = csr[i +12 + half];
        int s7 = csr[i +14 + half];
        float2 f0 = __half22float2(s2[(size_t)s0*32 + le]);
        float2 f1 = __half22float2(s2[(size_t)s1*32 + le]);
        float2 f2 = __half22float2(s2[(size_t)s2i*32 + le]);
        float2 f3 = __half22float2(s2[(size_t)s3*32 + le]);
        float2 f4 = __half22float2(s2[(size_t)s4*32 + le]);
        float2 f5 = __half22float2(s2[(size_t)s5*32 + le]);
        float2 f6 = __half22float2(s2[(size_t)s6*32 + le]);
        float2 f7 = __half22float2(s2[(size_t)s7*32 + le]);
        ax0 += f0.x; ay0 += f0.y;
        ax1 += f1.x; ay1 += f1.y;
        ax2 += f2.x; ay2 += f2.y;
        ax3 += f3.x; ay3 += f3.y;
        ax4 += f4.x; ay4 += f4.y;
        ax5 += f5.x; ay5 += f5.y;
        ax6 += f6.x; ay6 += f6.y;
        ax7 += f7.x; ay7 += f7.y;
      }
      for (; i + 2 <= e; i += 2){
        int src = csr[i + half];
        float2 f = __half22float2(s2[(size_t)src*32 + le]);
        ax0 += f.x; ay0 += f.y;
      }
      if (half == 0){
        if (i < e){
          float2 f = __half22float2(s2[(size_t)csr[i]*32 + le]);
          ax1 += f.x; ay1 += f.y;
        }
        float2 f = __half22float2(s2[(size_t)node*32 + le]);   // self loop
        ax2 += f.x; ay2 += f.y;
      }
      sx = ((ax0+ax1)+(ax2+ax3)) + ((ax4+ax5)+(ax6+ax7));
      sy = ((ay0+ay1)+(ay2+ay3)) + ((ay4+ay5)+(ay6+ay7));
      sx += __shfl_xor(sx, 32, 64);
      sy += __shfl_xor(sy, 32, 64);
    }
    if (half == 0){
      xs[wv*4+q][2*le]   = sx;
      xs[wv*4+q][2*le+1] = sy;
    }
  }
  __syncthreads();

  int f = tid&63, nq = tid>>6;
  float acc0=0.f, acc1=0.f, acc2=0.f, acc3=0.f;
  #pragma unroll 16
  for (int k=0;k<ND;k++){
    float w = wcs[k*ND+f];
    acc0 += w*xs[nq*4+0][k];
    acc1 += w*xs[nq*4+1][k];
    acc2 += w*xs[nq*4+2][k];
    acc3 += w*xs[nq*4+3][k];
  }
  int n0 = nb + nq*4;
  float bcf = bcs[f];
  #pragma unroll
  for (int j=0; j<4; ++j){
    int node = n0 + j;
    if (node < N){
      float a = (j==0)?acc0:(j==1)?acc1:(j==2)?acc2:acc3;
      float dn = dinv[node];
      float r = fmaxf(dn*a + bcf, 0.f);
      s_new[(size_t)node*ND+f] = __float2half_rn(dn*r);
      if (wout) outf[(size_t)node*ND+f] = r;
    }
  }
}

// ---------------- per-graph contiguous ranges (batch is sorted) ----------------
__global__ void k_goff(const int* __restrict__ batch, int* __restrict__ goff, int N, int B){
  int i = blockIdx.x*blockDim.x + threadIdx.x;
  if (i >= N) return;
  int b = batch[i];
  if (i == 0){ for (int g2=0; g2<=b; ++g2) goff[g2]=0; }
  else {
    int bp = batch[i-1];
    for (int g2=bp+1; g2<=b; ++g2) goff[g2]=i;
  }
  if (i == N-1){ for (int g2=b+1; g2<=B; ++g2) goff[g2]=N; }
}

// ---------------- LSTM step (8 graphs per block) ----------------
__global__ void k_lstm(const float* __restrict__ Wih, const float* __restrict__ Whh,
                       const float* __restrict__ bih, const float* __restrict__ bhh,
                       float* __restrict__ qs, float* __restrict__ hl, float* __restrict__ cl){
  __shared__ float qsr[8][128];
  __shared__ float hlr[8][64];
  __shared__ float gat[8][256];
  int tid = threadIdx.x;
  int g0 = blockIdx.x*8;
  for (int i=tid; i<8*128; i+=256){ int gg=i>>7, k=i&127; qsr[gg][k] = qs[(size_t)(g0+gg)*128+k]; }
  for (int i=tid; i<8*64;  i+=256){ int gg=i>>6, k=i&63;  hlr[gg][k] = hl[(size_t)(g0+gg)*64+k]; }
  __syncthreads();
  int j = tid;  // gate index 0..255
  float bb = bih[j] + bhh[j];
  float acc[8];
  #pragma unroll
  for (int gg=0; gg<8; gg++) acc[gg] = bb;
  const float* wr = Wih + (size_t)j*128;
  for (int k=0; k<128; k++){
    float w = wr[k];
    #pragma unroll
    for (int gg=0; gg<8; gg++) acc[gg] += w*qsr[gg][k];
  }
  const float* wr2 = Whh + (size_t)j*64;
  for (int k=0; k<64; k++){
    float w = wr2[k];
    #pragma unroll
    for (int gg=0; gg<8; gg++) acc[gg] += w*hlr[gg][k];
  }
  #pragma unroll
  for (int gg=0; gg<8; gg++) gat[gg][j] = acc[gg];
  __syncthreads();
  #pragma unroll
  for (int it=0; it<2; ++it){
    int idx = it*256 + tid;
    int gg = idx>>6, d = idx&63;
    int graph = g0+gg;
    float ig = sigmoidf_(gat[gg][d]);
    float fg = sigmoidf_(gat[gg][64+d]);
    float gv = tanhf(gat[gg][128+d]);
    float og = sigmoidf_(gat[gg][192+d]);
    float c = fg*cl[(size_t)graph*64+d] + ig*gv;
    float h = og*tanhf(c);
    cl[(size_t)graph*64+d] = c;
    hl[(size_t)graph*64+d] = h;
    qs[(size_t)graph*128+d] = h;   // q part of q_star
  }
}

// ---------------- attention pooling, one online-softmax sweep ----------------
__global__ void k_attn(const float* __restrict__ out, const int* __restrict__ goff,
                       const float* __restrict__ hl, float* __restrict__ qs){
  __shared__ float redm[4], redd[4];
  __shared__ float redr[4][64];
  int g = blockIdx.x;
  int tid = threadIdx.x, lane = tid&63, wv = tid>>6;
  int s = goff[g], e = goff[g+1];
  float q = hl[(size_t)g*64+lane];
  float m = -3.0e38f, denom = 0.f, racc = 0.f;
  for (int n=s+wv; n<e; n+=4){
    float v = out[(size_t)n*64+lane];
    float p = v*q;
    #pragma unroll
    for (int off=32; off>=1; off>>=1) p += __shfl_xor(p, off, 64);
    if (p > m){                      // wave-uniform branch
      float sc = __expf(m - p);      // first time: exp(-huge) -> 0
      denom *= sc; racc *= sc; m = p;
    }
    float w = __expf(p - m);
    denom += w; racc += w*v;
  }
  if (lane==0){ redm[wv] = m; redd[wv] = denom; }
  redr[wv][lane] = racc;
  __syncthreads();
  if (wv==0){
    float m0=redm[0], m1=redm[1], m2=redm[2], m3=redm[3];
    float mm = fmaxf(fmaxf(m0,m1), fmaxf(m2,m3));
    float s0=__expf(m0-mm), s1=__expf(m1-mm), s2=__expf(m2-mm), s3=__expf(m3-mm);
    float dt = redd[0]*s0 + redd[1]*s1 + redd[2]*s2 + redd[3]*s3;
    float rs = redr[0][lane]*s0 + redr[1][lane]*s1 + redr[2][lane]*s2 + redr[3][lane]*s3;
    qs[(size_t)g*128+64+lane] = (dt > 0.f) ? rs/dt : 0.f;
  }
}

// ---------------- final MLP ----------------
__global__ void k_final(const float* __restrict__ qs, const float* __restrict__ W1,
                        const float* __restrict__ b1, const float* __restrict__ W2,
                        const float* __restrict__ b2, float* __restrict__ outy){
  __shared__ float qsr[128];
  __shared__ float yy[64];
  int g = blockIdx.x; int t = threadIdx.x;  // 64 threads
  qsr[t]    = qs[(size_t)g*128 + t];
  qsr[64+t] = qs[(size_t)g*128 + 64 + t];
  __syncthreads();
  float acc = b1[t];
  for (int k=0; k<128; k++) acc += qsr[k]*W1[k*64+t];
  yy[t] = fmaxf(acc, 0.f);
  __syncthreads();
  if (t < 12){
    float a2 = b2[t];
    for (int k=0; k<64; k++) a2 += yy[k]*W2[k*12+t];
    outy[(size_t)g*12 + t] = a2;
  }
}

extern "C" void kernel_launch(void* const* d_in, const int* in_sizes, int n_in,
                              void* d_out, int out_size, void* d_ws, size_t ws_size,
                              hipStream_t stream){
  const float* x    = (const float*)d_in[0];
  const int*   ei   = (const int*)d_in[1];
  const int*   batch= (const int*)d_in[2];
  const float* W0   = (const float*)d_in[3];
  const float* b0   = (const float*)d_in[4];
  const float* Wc   = (const float*)d_in[5];
  const float* bc   = (const float*)d_in[6];
  const float* Wih  = (const float*)d_in[7];
  const float* Whh  = (const float*)d_in[8];
  const float* bih  = (const float*)d_in[9];
  const float* bhh  = (const float*)d_in[10];
  const float* W1   = (const float*)d_in[11];
  const float* b1   = (const float*)d_in[12];
  const float* W2   = (const float*)d_in[13];
  const float* b2   = (const float*)d_in[14];
  float* yout = (float*)d_out;

  const int N = in_sizes[0]/15;
  const int E = in_sizes[1]/2;
  const int B = out_size/12;
  const int NBK = (N + (1<<BKT_SHIFT) - 1) >> BKT_SHIFT;   // 196 <= 256
  const int* row = ei;       // sources
  const int* col = ei + E;   // targets

  char* ws = (char*)d_ws;
  size_t off = 0;
  auto alloc = [&](size_t bytes)->void*{
    void* p = ws + off; off = (off + bytes + 255) & ~(size_t)255; return p;
  };
  int*      bgcnt   = (int*)     alloc((size_t)(NBK+1)*4);
  int*      bstart  = (int*)     alloc((size_t)(NBK+1)*4);
  int*      bcur    = (int*)     alloc((size_t)NBK*BCUR_PAD*4);
  int*      rowptr  = (int*)     alloc((size_t)(N+1)*4);
  unsigned* pairs   = (unsigned*)alloc((size_t)E*4);
  int*      csr     = (int*)     alloc((size_t)E*4);
  float*    dinv    = (float*)   alloc((size_t)N*4);
  float*    nodef   = (float*)   alloc((size_t)N*ND*4);
  __half*   s_a     = (__half*)  alloc((size_t)N*ND*2);
  __half*   s_b     = (__half*)  alloc((size_t)N*ND*2);
  int*      goff    = (int*)     alloc((size_t)(B+1)*4);
  float*    hl      = (float*)   alloc((size_t)B*64*4);
  float*    cl      = (float*)   alloc((size_t)B*64*4);
  float*    qs      = (float*)   alloc((size_t)B*128*4);
  (void)ws_size; (void)n_in;

  hipMemsetAsync(bgcnt, 0, (size_t)(NBK+1)*4, stream);
  hipMemsetAsync(hl,   0, (size_t)B*64*4, stream);
  hipMemsetAsync(cl,   0, (size_t)B*64*4, stream);
  hipMemsetAsync(qs,   0, (size_t)B*128*4, stream);

  int nstg = (E + STG_TILE - 1)/STG_TILE;
  k_bhist <<<nstg, 256, 0, stream>>>(col, bgcnt, E, NBK);
  k_bscan <<<1, 256, 0, stream>>>(bgcnt, bstart, rowptr, NBK, E, N);
  k_bcinit<<<(NBK+255)/256, 256, 0, stream>>>(bstart, bcur, NBK);
  k_stage2<<<nstg, 256, 0, stream>>>(row, col, bcur, pairs, E, NBK);
  k_place <<<NBK, 256, 0, stream>>>(pairs, bstart, rowptr, dinv, csr, N);

  k_input<<<(N+3)/4, 256, 0, stream>>>(x, W0, b0, dinv, s_a, N);
  __half* scur = s_a; __half* snxt = s_b;
  for (int s6=0; s6<6; ++s6){
    k_prop<<<(N+15)/16, 256, 0, stream>>>((const __half2*)scur, rowptr, csr, dinv,
                                          Wc, bc, snxt, nodef, N, (s6==5)?1:0);
    __half* t = scur; scur = snxt; snxt = t;
  }

  k_goff<<<(N+255)/256, 256, 0, stream>>>(batch, goff, N, B);
  for (int s6=0; s6<6; ++s6){
    k_lstm<<<B/8, 256, 0, stream>>>(Wih, Whh, bih, bhh, qs, hl, cl);
    k_attn<<<B,   256, 0, stream>>>(nodef, goff, hl, qs);
  }
  k_final<<<B, 64, 0, stream>>>(qs, W1, b1, W2, b2, yout);
}

// Round 8
// 921.207 us; speedup vs baseline: 3.2406x; 1.1538x over previous
//
#include <hip/hip_runtime.h>
#include <hip/hip_fp16.h>
#include <math.h>

#define ND 64
constexpr int BKT_SHIFT = 9;          // 512 nodes per bucket; NBK = ceil(100k/512) = 196 <= 256
constexpr int BKT_MASK = (1 << BKT_SHIFT) - 1;
constexpr int BCUR_PAD = 16;          // ints -> 64 B per cursor
constexpr int STG_TILE = 8192;        // edges per stage block

__device__ __forceinline__ float sigmoidf_(float x){ return 1.f/(1.f+__expf(-x)); }
__device__ __forceinline__ __half2 h2lo(uint2 v){ return *reinterpret_cast<__half2*>(&v.x); }
__device__ __forceinline__ __half2 h2hi(uint2 v){ return *reinterpret_cast<__half2*>(&v.y); }
__device__ __forceinline__ __half2 shxor_h2(__half2 h, int off){
  unsigned u = *reinterpret_cast<unsigned*>(&h);
  u = __shfl_xor(u, off, 64);
  return *reinterpret_cast<__half2*>(&u);
}

// ---------------- bucket-hierarchical CSR build ----------------
__global__ void k_bhist(const int* __restrict__ col, int* __restrict__ bgcnt,
                        int E, int NBK){
  __shared__ int lhist[512];
  int t0 = blockIdx.x * STG_TILE;
  int t1 = t0 + STG_TILE; if (t1 > E) t1 = E;
  for (int i = threadIdx.x; i < NBK; i += 256) lhist[i] = 0;
  __syncthreads();
  for (int i = t0 + threadIdx.x; i < t1; i += 256)
    atomicAdd(&lhist[col[i] >> BKT_SHIFT], 1);
  __syncthreads();
  for (int i = threadIdx.x; i < NBK; i += 256)
    if (lhist[i] > 0) atomicAdd(&bgcnt[i], lhist[i]);
}

__global__ void k_bscan(const int* __restrict__ bgcnt, int* __restrict__ bstart,
                        int* __restrict__ rowptr, int NBK, int E, int N){
  __shared__ int tmp[256];
  int t = threadIdx.x;
  int v = (t < NBK) ? bgcnt[t] : 0;
  tmp[t] = v; __syncthreads();
  for (int off=1; off<256; off<<=1){
    int u = (t>=off) ? tmp[t-off] : 0;
    __syncthreads();
    tmp[t] += u;
    __syncthreads();
  }
  if (t <= NBK) bstart[t] = (t==0) ? 0 : tmp[t-1];
  if (t == 0) rowptr[N] = E;
}

__global__ void k_bcinit(const int* __restrict__ bstart, int* __restrict__ bcur, int NBK){
  int b = blockIdx.x*blockDim.x + threadIdx.x;
  if (b < NBK) bcur[b*BCUR_PAD] = bstart[b];
}

__global__ void k_stage2(const int* __restrict__ row, const int* __restrict__ col,
                         int* __restrict__ bcur, unsigned* __restrict__ pairs,
                         int E, int NBK){
  __shared__ int lhist[512];
  __shared__ int lbase[512];
  int t0 = blockIdx.x * STG_TILE;
  int t1 = t0 + STG_TILE; if (t1 > E) t1 = E;
  for (int i = threadIdx.x; i < NBK; i += 256) lhist[i] = 0;
  __syncthreads();
  for (int i = t0 + threadIdx.x; i < t1; i += 256)
    atomicAdd(&lhist[col[i] >> BKT_SHIFT], 1);
  __syncthreads();
  for (int i = threadIdx.x; i < NBK; i += 256){
    int c = lhist[i];
    lbase[i] = (c > 0) ? atomicAdd(&bcur[i*BCUR_PAD], c) : 0;
    lhist[i] = 0;
  }
  __syncthreads();
  for (int i = t0 + threadIdx.x; i < t1; i += 256){
    int d = col[i];
    int b = d >> BKT_SHIFT;
    int pos = lbase[b] + atomicAdd(&lhist[b], 1);
    pairs[pos] = ((unsigned)row[i] << BKT_SHIFT) | (unsigned)(d & BKT_MASK);
  }
}

__global__ void k_place(const unsigned* __restrict__ pairs, const int* __restrict__ bstart,
                        int* __restrict__ rowptr, float* __restrict__ dinv,
                        int* __restrict__ csr, int N){
  __shared__ int h[1 << BKT_SHIFT];
  __shared__ int excl[1 << BKT_SHIFT];
  __shared__ int tsum[256];
  int b = blockIdx.x;
  int base = b << BKT_SHIFT;
  int nend = base + (1 << BKT_SHIFT); if (nend > N) nend = N;
  int cnt = nend - base;
  int t = threadIdx.x;
  int s = bstart[b], e = bstart[b+1];

  h[2*t] = 0; h[2*t+1] = 0;
  __syncthreads();
  for (int i = s + t; i < e; i += 256)
    atomicAdd(&h[pairs[i] & BKT_MASK], 1);
  __syncthreads();
  int a0 = h[2*t], a1 = h[2*t+1];
  tsum[t] = a0 + a1;
  __syncthreads();
  for (int off=1; off<256; off<<=1){
    int u = (t>=off) ? tsum[t-off] : 0;
    __syncthreads();
    tsum[t] += u;
    __syncthreads();
  }
  int base0 = (t==0) ? 0 : tsum[t-1];
  excl[2*t]   = base0;
  excl[2*t+1] = base0 + a0;
  __syncthreads();
  for (int c = t; c < cnt; c += 256){
    int deg = h[c];
    rowptr[base + c] = s + excl[c];
    dinv[base + c] = rsqrtf((float)(deg + 1));   // +1 = self loop
  }
  __syncthreads();
  for (int c = t; c < cnt; c += 256) h[c] = s + excl[c];
  __syncthreads();
  for (int i = s + t; i < e; i += 256){
    unsigned p = pairs[i];
    int pos = atomicAdd(&h[p & BKT_MASK], 1);
    csr[pos] = (int)(p >> BKT_SHIFT);
  }
}

// ---------------- input MLP: s0 = fp16( dinv * relu(x @ W0 + b0) ) ----------------
__global__ void k_input(const float* __restrict__ x, const float* __restrict__ W0,
                        const float* __restrict__ b0, const float* __restrict__ dinv,
                        __half* __restrict__ s, int N){
  __shared__ float w0s[15*ND];
  __shared__ float b0s[ND];
  int tid = threadIdx.x;
  for (int i=tid; i<15*ND; i+=256) w0s[i] = W0[i];
  if (tid < ND) b0s[tid] = b0[tid];
  __syncthreads();
  int node = blockIdx.x*4 + (tid>>6);
  int f = tid & 63;
  if (node < N){
    float acc = b0s[f];
    const float* xr = x + (size_t)node*15;
    #pragma unroll
    for (int k=0;k<15;k++) acc += xr[k]*w0s[k*ND+f];
    s[(size_t)node*ND+f] = __float2half_rn(dinv[node]*fmaxf(acc, 0.f));
  }
}

// ---------------- fused propagation step, packed-fp16 gather ----------------
// wave = 4 groups x 16 lanes; one load instruction fetches 4 rows (dwordx2/lane);
// accumulate with __hadd2 packed adds; 2 shfl_xor levels combine groups;
// self-loop added post-reduction; tail: group g takes edge i+g (summed once).
__global__ void k_prop(const __half* __restrict__ sbuf, const int* __restrict__ rowptr,
                       const int* __restrict__ csr, const float* __restrict__ dinv,
                       const float* __restrict__ Wc, const float* __restrict__ bc,
                       __half* __restrict__ s_new, __half* __restrict__ outh,
                       int N, int wout){
  __shared__ float wcs[ND*ND];
  __shared__ float xs[16][ND];
  __shared__ float bcs[ND];
  const uint2* g8 = (const uint2*)sbuf;
  int tid = threadIdx.x;
  for (int i=tid; i<ND*ND; i+=256) wcs[i] = Wc[i];
  if (tid < ND) bcs[tid] = bc[tid];
  int nb = blockIdx.x*16;
  int wv = tid>>6, lane = tid&63;
  int grp = lane>>4, li = lane&15;

  for (int q=0; q<4; ++q){
    int node = nb + wv*4 + q;
    float val = 0.f;
    if (node < N){
      int s = rowptr[node], e = rowptr[node+1];
      __half2 z = __float2half2_rn(0.f);
      __half2 a0x=z,a0y=z, a1x=z,a1y=z, a2x=z,a2y=z, a3x=z,a3y=z;
      int i = s;
      for (; i + 16 <= e; i += 16){
        int s0 = csr[i +  0 + grp];
        int s1 = csr[i +  4 + grp];
        int s2 = csr[i +  8 + grp];
        int s3 = csr[i + 12 + grp];
        uint2 v0 = g8[(size_t)s0*16 + li];
        uint2 v1 = g8[(size_t)s1*16 + li];
        uint2 v2 = g8[(size_t)s2*16 + li];
        uint2 v3 = g8[(size_t)s3*16 + li];
        a0x = __hadd2(a0x, h2lo(v0)); a0y = __hadd2(a0y, h2hi(v0));
        a1x = __hadd2(a1x, h2lo(v1)); a1y = __hadd2(a1y, h2hi(v1));
        a2x = __hadd2(a2x, h2lo(v2)); a2y = __hadd2(a2y, h2hi(v2));
        a3x = __hadd2(a3x, h2lo(v3)); a3y = __hadd2(a3y, h2hi(v3));
      }
      for (; i + 4 <= e; i += 4){
        int s0 = csr[i + grp];
        uint2 v0 = g8[(size_t)s0*16 + li];
        a0x = __hadd2(a0x, h2lo(v0)); a0y = __hadd2(a0y, h2hi(v0));
      }
      int r = e - i;
      if (grp < r){
        int s0 = csr[i + grp];
        uint2 v0 = g8[(size_t)s0*16 + li];
        a1x = __hadd2(a1x, h2lo(v0)); a1y = __hadd2(a1y, h2hi(v0));
      }
      __half2 sxh = __hadd2(__hadd2(a0x,a1x), __hadd2(a2x,a3x));
      __half2 syh = __hadd2(__hadd2(a0y,a1y), __hadd2(a2y,a3y));
      sxh = __hadd2(sxh, shxor_h2(sxh, 16));
      syh = __hadd2(syh, shxor_h2(syh, 16));
      sxh = __hadd2(sxh, shxor_h2(sxh, 32));
      syh = __hadd2(syh, shxor_h2(syh, 32));
      uint2 sv = g8[(size_t)node*16 + li];        // self loop
      sxh = __hadd2(sxh, h2lo(sv));
      syh = __hadd2(syh, h2hi(sv));
      val = (grp==0) ? __half2float(__low2half(sxh))
          : (grp==1) ? __half2float(__high2half(sxh))
          : (grp==2) ? __half2float(__low2half(syh))
          :            __half2float(__high2half(syh));
    }
    xs[wv*4+q][4*li+grp] = val;    // bank = (4*li+grp)%32 -> 2 lanes/bank, free
  }
  __syncthreads();

  int f = tid&63, nq = tid>>6;
  float acc0=0.f, acc1=0.f, acc2=0.f, acc3=0.f;
  #pragma unroll 16
  for (int k=0;k<ND;k++){
    float w = wcs[k*ND+f];
    acc0 += w*xs[nq*4+0][k];
    acc1 += w*xs[nq*4+1][k];
    acc2 += w*xs[nq*4+2][k];
    acc3 += w*xs[nq*4+3][k];
  }
  int n0 = nb + nq*4;
  float bcf = bcs[f];
  #pragma unroll
  for (int j=0; j<4; ++j){
    int node = n0 + j;
    if (node < N){
      float a = (j==0)?acc0:(j==1)?acc1:(j==2)?acc2:acc3;
      float dn = dinv[node];
      float r = fmaxf(dn*a + bcf, 0.f);
      s_new[(size_t)node*ND+f] = __float2half_rn(dn*r);
      if (wout) outh[(size_t)node*ND+f] = __float2half_rn(r);
    }
  }
}

// ---------------- per-graph contiguous ranges (batch is sorted) ----------------
__global__ void k_goff(const int* __restrict__ batch, int* __restrict__ goff, int N, int B){
  int i = blockIdx.x*blockDim.x + threadIdx.x;
  if (i >= N) return;
  int b = batch[i];
  if (i == 0){ for (int g2=0; g2<=b; ++g2) goff[g2]=0; }
  else {
    int bp = batch[i-1];
    for (int g2=bp+1; g2<=b; ++g2) goff[g2]=i;
  }
  if (i == N-1){ for (int g2=b+1; g2<=B; ++g2) goff[g2]=N; }
}

// ---------------- LSTM step (8 graphs per block) ----------------
__global__ void k_lstm(const float* __restrict__ Wih, const float* __restrict__ Whh,
                       const float* __restrict__ bih, const float* __restrict__ bhh,
                       float* __restrict__ qs, float* __restrict__ hl, float* __restrict__ cl){
  __shared__ float qsr[8][128];
  __shared__ float hlr[8][64];
  __shared__ float gat[8][256];
  int tid = threadIdx.x;
  int g0 = blockIdx.x*8;
  for (int i=tid; i<8*128; i+=256){ int gg=i>>7, k=i&127; qsr[gg][k] = qs[(size_t)(g0+gg)*128+k]; }
  for (int i=tid; i<8*64;  i+=256){ int gg=i>>6, k=i&63;  hlr[gg][k] = hl[(size_t)(g0+gg)*64+k]; }
  __syncthreads();
  int j = tid;
  float bb = bih[j] + bhh[j];
  float acc[8];
  #pragma unroll
  for (int gg=0; gg<8; gg++) acc[gg] = bb;
  const float* wr = Wih + (size_t)j*128;
  for (int k=0; k<128; k++){
    float w = wr[k];
    #pragma unroll
    for (int gg=0; gg<8; gg++) acc[gg] += w*qsr[gg][k];
  }
  const float* wr2 = Whh + (size_t)j*64;
  for (int k=0; k<64; k++){
    float w = wr2[k];
    #pragma unroll
    for (int gg=0; gg<8; gg++) acc[gg] += w*hlr[gg][k];
  }
  #pragma unroll
  for (int gg=0; gg<8; gg++) gat[gg][j] = acc[gg];
  __syncthreads();
  #pragma unroll
  for (int it=0; it<2; ++it){
    int idx = it*256 + tid;
    int gg = idx>>6, d = idx&63;
    int graph = g0+gg;
    float ig = sigmoidf_(gat[gg][d]);
    float fg = sigmoidf_(gat[gg][64+d]);
    float gv = tanhf(gat[gg][128+d]);
    float og = sigmoidf_(gat[gg][192+d]);
    float c = fg*cl[(size_t)graph*64+d] + ig*gv;
    float h = og*tanhf(c);
    cl[(size_t)graph*64+d] = c;
    hl[(size_t)graph*64+d] = h;
    qs[(size_t)graph*128+d] = h;
  }
}

// ---------------- attention pooling, one online-softmax sweep (fp16 feats) ----------------
__global__ void k_attn(const __half* __restrict__ out, const int* __restrict__ goff,
                       const float* __restrict__ hl, float* __restrict__ qs){
  __shared__ float redm[4], redd[4];
  __shared__ float redr[4][64];
  int g = blockIdx.x;
  int tid = threadIdx.x, lane = tid&63, wv = tid>>6;
  int s = goff[g], e = goff[g+1];
  float q = hl[(size_t)g*64+lane];
  float m = -3.0e38f, denom = 0.f, racc = 0.f;
  for (int n=s+wv; n<e; n+=4){
    float v = __half2float(out[(size_t)n*64+lane]);
    float p = v*q;
    #pragma unroll
    for (int off=32; off>=1; off>>=1) p += __shfl_xor(p, off, 64);
    if (p > m){
      float sc = __expf(m - p);
      denom *= sc; racc *= sc; m = p;
    }
    float w = __expf(p - m);
    denom += w; racc += w*v;
  }
  if (lane==0){ redm[wv] = m; redd[wv] = denom; }
  redr[wv][lane] = racc;
  __syncthreads();
  if (wv==0){
    float m0=redm[0], m1=redm[1], m2=redm[2], m3=redm[3];
    float mm = fmaxf(fmaxf(m0,m1), fmaxf(m2,m3));
    float s0=__expf(m0-mm), s1=__expf(m1-mm), s2=__expf(m2-mm), s3=__expf(m3-mm);
    float dt = redd[0]*s0 + redd[1]*s1 + redd[2]*s2 + redd[3]*s3;
    float rs = redr[0][lane]*s0 + redr[1][lane]*s1 + redr[2][lane]*s2 + redr[3][lane]*s3;
    qs[(size_t)g*128+64+lane] = (dt > 0.f) ? rs/dt : 0.f;
  }
}

// ---------------- final MLP ----------------
__global__ void k_final(const float* __restrict__ qs, const float* __restrict__ W1,
                        const float* __restrict__ b1, const float* __restrict__ W2,
                        const float* __restrict__ b2, float* __restrict__ outy){
  __shared__ float qsr[128];
  __shared__ float yy[64];
  int g = blockIdx.x; int t = threadIdx.x;
  qsr[t]    = qs[(size_t)g*128 + t];
  qsr[64+t] = qs[(size_t)g*128 + 64 + t];
  __syncthreads();
  float acc = b1[t];
  for (int k=0; k<128; k++) acc += qsr[k]*W1[k*64+t];
  yy[t] = fmaxf(acc, 0.f);
  __syncthreads();
  if (t < 12){
    float a2 = b2[t];
    for (int k=0; k<64; k++) a2 += yy[k]*W2[k*12+t];
    outy[(size_t)g*12 + t] = a2;
  }
}

extern "C" void kernel_launch(void* const* d_in, const int* in_sizes, int n_in,
                              void* d_out, int out_size, void* d_ws, size_t ws_size,
                              hipStream_t stream){
  const float* x    = (const float*)d_in[0];
  const int*   ei   = (const int*)d_in[1];
  const int*   batch= (const int*)d_in[2];
  const float* W0   = (const float*)d_in[3];
  const float* b0   = (const float*)d_in[4];
  const float* Wc   = (const float*)d_in[5];
  const float* bc   = (const float*)d_in[6];
  const float* Wih  = (const float*)d_in[7];
  const float* Whh  = (const float*)d_in[8];
  const float* bih  = (const float*)d_in[9];
  const float* bhh  = (const float*)d_in[10];
  const float* W1   = (const float*)d_in[11];
  const float* b1   = (const float*)d_in[12];
  const float* W2   = (const float*)d_in[13];
  const float* b2   = (const float*)d_in[14];
  float* yout = (float*)d_out;

  const int N = in_sizes[0]/15;
  const int E = in_sizes[1]/2;
  const int B = out_size/12;
  const int NBK = (N + (1<<BKT_SHIFT) - 1) >> BKT_SHIFT;
  const int* row = ei;
  const int* col = ei + E;

  char* ws = (char*)d_ws;
  size_t off = 0;
  auto alloc = [&](size_t bytes)->void*{
    void* p = ws + off; off = (off + bytes + 255) & ~(size_t)255; return p;
  };
  int*      bgcnt   = (int*)     alloc((size_t)(NBK+1)*4);
  int*      bstart  = (int*)     alloc((size_t)(NBK+1)*4);
  int*      bcur    = (int*)     alloc((size_t)NBK*BCUR_PAD*4);
  int*      rowptr  = (int*)     alloc((size_t)(N+1)*4);
  unsigned* pairs   = (unsigned*)alloc((size_t)E*4);
  int*      csr     = (int*)     alloc((size_t)E*4);
  float*    dinv    = (float*)   alloc((size_t)N*4);
  __half*   nodef   = (__half*)  alloc((size_t)N*ND*2);
  __half*   s_a     = (__half*)  alloc((size_t)N*ND*2);
  __half*   s_b     = (__half*)  alloc((size_t)N*ND*2);
  int*      goff    = (int*)     alloc((size_t)(B+1)*4);
  float*    hl      = (float*)   alloc((size_t)B*64*4);
  float*    cl      = (float*)   alloc((size_t)B*64*4);
  float*    qs      = (float*)   alloc((size_t)B*128*4);
  (void)ws_size; (void)n_in;

  hipMemsetAsync(bgcnt, 0, (size_t)(NBK+1)*4, stream);
  hipMemsetAsync(hl,   0, (size_t)B*64*4, stream);
  hipMemsetAsync(cl,   0, (size_t)B*64*4, stream);
  hipMemsetAsync(qs,   0, (size_t)B*128*4, stream);

  int nstg = (E + STG_TILE - 1)/STG_TILE;
  k_bhist <<<nstg, 256, 0, stream>>>(col, bgcnt, E, NBK);
  k_bscan <<<1, 256, 0, stream>>>(bgcnt, bstart, rowptr, NBK, E, N);
  k_bcinit<<<(NBK+255)/256, 256, 0, stream>>>(bstart, bcur, NBK);
  k_stage2<<<nstg, 256, 0, stream>>>(row, col, bcur, pairs, E, NBK);
  k_place <<<NBK, 256, 0, stream>>>(pairs, bstart, rowptr, dinv, csr, N);

  k_input<<<(N+3)/4, 256, 0, stream>>>(x, W0, b0, dinv, s_a, N);
  __half* scur = s_a; __half* snxt = s_b;
  for (int s6=0; s6<6; ++s6){
    k_prop<<<(N+15)/16, 256, 0, stream>>>(scur, rowptr, csr, dinv,
                                          Wc, bc, snxt, nodef, N, (s6==5)?1:0);
    __half* t = scur; scur = snxt; snxt = t;
  }

  k_goff<<<(N+255)/256, 256, 0, stream>>>(batch, goff, N, B);
  for (int s6=0; s6<6; ++s6){
    k_lstm<<<B/8, 256, 0, stream>>>(Wih, Whh, bih, bhh, qs, hl, cl);
    k_attn<<<B,   256, 0, stream>>>(nodef, goff, hl, qs);
  }
  k_final<<<B, 64, 0, stream>>>(qs, W1, b1, W2, b2, yout);
}